// Round 8
// baseline (5849.487 us; speedup 1.0000x reference)
//
#include <hip/hip_runtime.h>
#include <hip/hip_bf16.h>

// FARGAN vocoder on MI355X. Sizes fixed by the reference:
#define SS      64
#define NSUB    4
#define LPREV   512
#define NF      193
#define NFRAMES 100
#define BATCH   64
#define RPW     16     // batch rows per workgroup (MFMA M)

typedef __attribute__((ext_vector_type(8))) short   short8;   // 8 bf16 (4 VGPRs)
typedef __attribute__((ext_vector_type(4))) float   floatx4;  // MFMA C/D

// ---------- scalar helpers ----------
__device__ __forceinline__ float bf2f(unsigned short u) {
    return __uint_as_float(((unsigned int)u) << 16);
}
__device__ __forceinline__ unsigned short f2bf(float x) {
    unsigned int u = __float_as_uint(x);
    return (unsigned short)((u + 0x7fffu + ((u >> 16) & 1u)) >> 16);
}
__device__ __forceinline__ unsigned int packbf(float a, float b) {
    return (unsigned int)f2bf(a) | ((unsigned int)f2bf(b) << 16);
}
__device__ __forceinline__ float fexp2(float x) {
#if __has_builtin(__builtin_amdgcn_exp2f)
    return __builtin_amdgcn_exp2f(x);
#else
    return exp2f(x);
#endif
}
__device__ __forceinline__ float frcp(float x) {
#if __has_builtin(__builtin_amdgcn_rcpf)
    return __builtin_amdgcn_rcpf(x);
#else
    return 1.0f / x;
#endif
}
__device__ __forceinline__ float fsig(float x) {
    return frcp(1.0f + fexp2(-1.442695041f * x));
}
__device__ __forceinline__ float ftanh(float x) {
    return fmaf(2.0f, frcp(1.0f + fexp2(-2.885390082f * x)), -1.0f);
}
__device__ __forceinline__ float ld1f(int f32, const void* p, size_t i) {
    if (f32) return ((const float*)p)[i];
    return bf2f(((const unsigned short*)p)[i]);
}
__device__ __forceinline__ float lo16(unsigned int u) { return __uint_as_float(u << 16); }
__device__ __forceinline__ float hi16(unsigned int u) { return __uint_as_float(u & 0xffff0000u); }

// MFMA wrapper
__device__ __forceinline__ floatx4 mf(short8 a, short8 b, floatx4 c) {
    return __builtin_amdgcn_mfma_f32_16x16x32_bf16(a, b, c, 0, 0, 0);
}

// select this wave-half's two C rows (h is wave-uniform)
__device__ __forceinline__ float2 selh(const floatx4 C, int h) {
    float2 v;
    if (h) { v.x = C[2]; v.y = C[3]; }
    else   { v.x = C[0]; v.y = C[1]; }
    return v;
}

// A-fragment from packed-bf16 LDS buffer: row m, k-block kb, quad q.
__device__ __forceinline__ short8 ldA(const unsigned short* buf, int strideU,
                                      int m, int kb, int q) {
    const unsigned int* p = (const unsigned int*)buf + m * strideU + kb * 16 + q * 4;
    uint4 u = *(const uint4*)p;
    return __builtin_bit_cast(short8, u);
}
// B-fragment from prepacked weight buffer
__device__ __forceinline__ short8 ldB(const uint4* __restrict__ w, int idx) {
    return __builtin_bit_cast(short8, w[idx]);
}

// ---------- wbuf layout (units = 16B frags) ----------
#define OFF_FW   0        // 4t x 13kb
#define OFF_FWG  3328     // 4t x 2kb
#define OFF_GRU(G) (3840 + 4608*(G))   // r@+0(6kb) z@+1536(6kb) i@+3072(4kb) h@+4096(2kb)
#define OFF_WG(G)  (17664 + 512*(G))   // 4t x 2kb
#define OFF_SD   19200    // 8t x 10kb
#define OFF_SG   24320    // 8t x 4kb
#define OFF_OUT  26368    // 4t x 4kb
#define NFRAG    27392

// ---------- dtype detector ----------
__global__ void fargan_detect(const void* feats, int* flag) {
    const float* pf = (const float*)feats;
    int ok = 1;
    for (int f = 0; f < 50; ++f) {
        float v = pf[192 * NFRAMES + f];
        if (!(v >= 63.0f && v <= 301.0f)) { ok = 0; break; }
    }
    *flag = ok;
}

// ---------- weight prep: repack all seq weights into frag order ----------
__global__ __launch_bounds__(256) void fargan_prep(
    const int* __restrict__ flag,
    const void* Wfw, const void* Wfwg,
    const void* Wih1, const void* Whh1, const void* Wih2, const void* Whh2,
    const void* Wih3, const void* Whh3,
    const void* Wg1, const void* Wg2, const void* Wg3,
    const void* Wsg, const void* Wsd, const void* Wout,
    uint4* __restrict__ wbuf)
{
    int fi = blockIdx.x * 256 + threadIdx.x;
    if (fi >= NFRAG) return;
    int f32 = *flag;
    const void* mats[14] = {Wfw, Wfwg, Wih1, Whh1, Wih2, Whh2, Wih3, Whh3,
                            Wg1, Wg2, Wg3, Wsg, Wsd, Wout};
    const int NSEG = 20;
    const int sb[NSEG]  = {0,3328, 3840,5376,6912,7936, 8448,9984,11520,12544,
                           13056,14592,16128,17152, 17664,18176,18688, 19200,24320,26368};
    const int sa[NSEG]  = {0,1, 2,2,2,3, 4,4,4,5, 6,6,6,7, 8,9,10, 12,11,13};
    const int sbx[NSEG] = {-1,-1, 3,3,-1,-1, 5,5,-1,-1, 7,7,-1,-1, -1,-1,-1, -1,-1,-1};
    const int sro[NSEG] = {0,0, 0,64,128,128, 0,64,128,128, 0,64,128,128, 0,0,0, 0,0,0};
    const int skb[NSEG] = {13,2, 6,6,4,2, 6,6,4,2, 6,6,4,2, 2,2,2, 10,4,4};
    const int ska[NSEG] = {388,64, 128,128,128,64, 128,128,128,64, 128,128,128,64,
                           64,64,64, 320,128,128};
    const int skr[NSEG] = {388,64, 192,192,128,64, 192,192,128,64, 192,192,128,64,
                           64,64,64, 320,128,128};
    int s = 0;
    for (int i = 1; i < NSEG; ++i) if (fi >= sb[i]) s = i;
    int local = fi - sb[s];
    int ln = local & 15, lq = (local >> 4) & 3, tkb = local >> 6;
    int KB = skb[s];
    int kb = tkb % KB, tile = tkb / KB;
    int row = sro[s] + tile * 16 + ln;
    int Ka = ska[s], Kr = skr[s];
    union { unsigned short h[8]; uint4 v; } u;
#pragma unroll
    for (int j = 0; j < 8; ++j) {
        int k = kb * 32 + lq * 8 + j;
        unsigned short val = 0;
        if (k < Kr) {
            const void* m; size_t off;
            if (sbx[s] >= 0 && k >= Ka) { m = mats[sbx[s]]; off = (size_t)row * 64 + (k - Ka); }
            else                        { m = mats[sa[s]];  off = (size_t)row * Ka + k; }
            val = f32 ? f2bf(((const float*)m)[off]) : ((const unsigned short*)m)[off];
        }
        u.h[j] = val;
    }
    wbuf[fi] = u.v;
}

// ---------- prep: repack Wc1/2/3 transposed + bf16-pair packed ----------
__global__ __launch_bounds__(256) void fargan_prep_conv(
    const int* __restrict__ flag,
    const void* Wc1, const void* Wc2, const void* Wc3,
    unsigned int* __restrict__ wct)
{
    int idx = blockIdx.x * 256 + threadIdx.x;
    if (idx >= 131072) return;
    int f32 = *flag;
    const void* W; int n, k2;
    if (idx < 32768)      { W = Wc1; k2 = idx >> 8, n = idx & 255; }
    else if (idx < 65536) { W = Wc2; k2 = (idx - 32768) >> 8; n = idx & 255; }
    else                  { W = Wc3; k2 = (idx - 65536) >> 9; n = (idx - 65536) & 511; }
    size_t off = (size_t)n * 256 + 2 * k2;
    unsigned int v;
    if (f32) {
        const float* p = (const float*)W + off;
        v = packbf(p[0], p[1]);
    } else {
        v = *(const unsigned int*)((const unsigned short*)W + off);
    }
    wct[idx] = v;
}

// ---------- kernel 1: frame conv (coalesced transposed weights) ----------
template<bool F32>
__device__ __forceinline__ void conv_body(
    const void* __restrict__ feats, const void* __restrict__ gfeat,
    const unsigned int* __restrict__ wct, float* __restrict__ cbuf)
{
    int blk = blockIdx.x;
    int b = blk / NFRAMES, f = blk - b * NFRAMES;
    int t = threadIdx.x;
    __shared__ float xa[256], xb[256];

    float v;
    if (t < 192) v = ld1f(F32 ? 1 : 0, feats, (size_t)b * (NF * NFRAMES) + t * NFRAMES + f);
    else         v = ld1f(F32 ? 1 : 0, gfeat, (size_t)b * 64 + (t - 192));
    xa[t] = v;
    __syncthreads();

    const unsigned int* w1 = wct;
    const unsigned int* w2 = wct + 32768;
    const unsigned int* w3 = wct + 65536;

    float a0 = 0.f, a1 = 0.f;
#pragma unroll 8
    for (int k2 = 0; k2 < 128; ++k2) {
        unsigned int u = w1[k2 * 256 + t];
        a0 = fmaf(lo16(u), xa[2 * k2], a0);
        a1 = fmaf(hi16(u), xa[2 * k2 + 1], a1);
    }
    xb[t] = ftanh(a0 + a1);
    __syncthreads();

    a0 = 0.f; a1 = 0.f;
#pragma unroll 8
    for (int k2 = 0; k2 < 128; ++k2) {
        unsigned int u = w2[k2 * 256 + t];
        a0 = fmaf(lo16(u), xb[2 * k2], a0);
        a1 = fmaf(hi16(u), xb[2 * k2 + 1], a1);
    }
    xa[t] = ftanh(a0 + a1);
    __syncthreads();

    a0 = 0.f; a1 = 0.f;
    float b0 = 0.f, b1 = 0.f;
#pragma unroll 8
    for (int k2 = 0; k2 < 128; ++k2) {
        unsigned int u = w3[k2 * 512 + t];
        unsigned int u2 = w3[k2 * 512 + t + 256];
        a0 = fmaf(lo16(u),  xa[2 * k2],     a0);
        a1 = fmaf(hi16(u),  xa[2 * k2 + 1], a1);
        b0 = fmaf(lo16(u2), xa[2 * k2],     b0);
        b1 = fmaf(hi16(u2), xa[2 * k2 + 1], b1);
    }
    float* co = cbuf + ((size_t)b * NFRAMES + f) * 512;
    int e0 = t, e1 = t + 256;
    co[(e0 & 3) * 128 + (e0 >> 2)] = ftanh(a0 + a1);
    co[(e1 & 3) * 128 + (e1 >> 2)] = ftanh(b0 + b1);
}

__global__ __launch_bounds__(256) void fargan_conv(
    const void* feats, const void* gfeat,
    const int* flag, const unsigned int* wct, float* cbuf)
{
    if (*flag) conv_body<true>(feats, gfeat, wct, cbuf);
    else       conv_body<false>(feats, gfeat, wct, cbuf);
}

// ---------- kernel 2: sequential recurrence ----------
// 4 WGs x 16 batch rows, 512 threads = 8 waves = 2 waves/SIMD.
// Wave pair (same w = w8&3) runs identical MFMAs redundantly; epilogues are
// split by C-row half h = w8>>2 (rows 4lq+2h, 4lq+2h+1). Same LDS, same
// barriers; co-resident wave fills the other's stall cycles.

__global__ __launch_bounds__(512, 1) void fargan_seq(
    const void* __restrict__ feats, const void* __restrict__ prev_in,
    const int* __restrict__ flag, const float* __restrict__ cbuf,
    const uint4* __restrict__ wbuf, void* __restrict__ outp)
{
    const int t = threadIdx.x;
    const int b0 = blockIdx.x * RPW;
    const int lane = t & 63, w8 = t >> 6;
    const int w = w8 & 3, h = w8 >> 2;
    const int lq = lane >> 4, ln = lane & 15;
    const int nj = 16 * w + ln;            // n for 64-wide layers
    const int m0 = 4 * lq + 2 * h;         // this wave's first epilogue row
    const int f32 = *flag;

    // ---- LDS (identical to R7) ----
    __shared__ __align__(16) unsigned short hist[RPW * 520];
    __shared__ __align__(16) unsigned short catb[RPW * 424];
    __shared__ __align__(16) unsigned short xg  [RPW * 200];
    __shared__ __align__(16) unsigned short skx [RPW * 328];
    __shared__ __align__(16) unsigned short sdbb[RPW * 136];
    __shared__ __align__(16) unsigned short sobb[RPW * 136];
    __shared__ __align__(16) unsigned short vpre[RPW * 72];
    __shared__ __align__(16) unsigned short svp [RPW * 72];
    __shared__ __align__(16) unsigned short wsd[128 * 328];
    __shared__ int period_s[RPW];

    // ---- resident B-fragments (per lane; pair-redundant) ----
    short8 Bfw[13], Bfwg[2], Bout[4];
    short8 Br[3][6], Bz[3][6], Bi[3][4], Bh[3][2], Bg[3][2];
    short8 Bsg[2][4];
#pragma unroll
    for (int kb = 0; kb < 13; ++kb) Bfw[kb] = ldB(wbuf, OFF_FW + (w * 13 + kb) * 64 + lane);
#pragma unroll
    for (int kb = 0; kb < 2; ++kb)  Bfwg[kb] = ldB(wbuf, OFF_FWG + (w * 2 + kb) * 64 + lane);
#pragma unroll
    for (int G = 0; G < 3; ++G) {
        const int OR = OFF_GRU(G), OZ = OR + 1536, OI = OR + 3072, OH = OR + 4096;
#pragma unroll
        for (int kb = 0; kb < 6; ++kb) {
            Br[G][kb] = ldB(wbuf, OR + (w * 6 + kb) * 64 + lane);
            Bz[G][kb] = ldB(wbuf, OZ + (w * 6 + kb) * 64 + lane);
        }
#pragma unroll
        for (int kb = 0; kb < 4; ++kb) Bi[G][kb] = ldB(wbuf, OI + (w * 4 + kb) * 64 + lane);
#pragma unroll
        for (int kb = 0; kb < 2; ++kb) {
            Bh[G][kb] = ldB(wbuf, OH + (w * 2 + kb) * 64 + lane);
            Bg[G][kb] = ldB(wbuf, OFF_WG(G) + (w * 2 + kb) * 64 + lane);
        }
    }
#pragma unroll
    for (int tile = 0; tile < 2; ++tile)
#pragma unroll
        for (int kb = 0; kb < 4; ++kb)
            Bsg[tile][kb] = ldB(wbuf, OFF_SG + ((2 * w + tile) * 4 + kb) * 64 + lane);
#pragma unroll
    for (int kb = 0; kb < 4; ++kb) Bout[kb] = ldB(wbuf, OFF_OUT + (w * 4 + kb) * 64 + lane);

    // ---- Wsd -> LDS from wbuf ----
    for (int fi = t; fi < 8 * 10 * 64; fi += 512) {
        int lane2 = fi & 63, tkb = fi >> 6;
        int kb = tkb % 10, tile = tkb / 10;
        int lq2 = lane2 >> 4, ln2 = lane2 & 15;
        int row = tile * 16 + ln2;
        uint4 v = wbuf[OFF_SD + fi];
        *(uint4*)((unsigned int*)wsd + row * 164 + kb * 16 + lq2 * 4) = v;
    }

    // ---- zero init LDS state + hist fill ----
    for (int i = t; i < RPW * 424; i += 512) catb[i] = 0;
    for (int i = t; i < RPW * 200; i += 512) xg[i] = 0;
    for (int i = t; i < RPW * 328; i += 512) skx[i] = 0;
    for (int i = t; i < RPW * 136; i += 512) { sdbb[i] = 0; sobb[i] = 0; }
    for (int i = t; i < RPW * 72;  i += 512) { vpre[i] = 0; svp[i] = 0; }
    for (int i = t; i < RPW * 512; i += 512) {
        int row = i >> 9, c = i & 511;
        hist[row * 520 + c] = f2bf(ld1f(f32, prev_in, (size_t)(b0 + row) * LPREV + c));
    }
    __syncthreads();
    // initial prev_sub slots (step 0)
    for (int i = t; i < RPW * 64; i += 512) {
        int row = i >> 6, c = i & 63;
        unsigned short hh = hist[row * 520 + 448 + c];
        catb[row * 424 + 128 + c] = hh;
        skx [row * 328 + 256 + c] = hh;
        xg  [row * 200 + 64  + c] = hh;
    }

    // GRU states: this wave's two rows only (m0, m0+1), col nj
    float svlo[3] = {0.f, 0.f, 0.f}, svhi[3] = {0.f, 0.f, 0.f};

    // ---- prefetch regs (32 threads/row) ----
    const int prow = t >> 5, ps32 = t & 31, pe4 = (t & 31) * 4;
    float pfc[4];
    {
        const float* cr0 = cbuf + ((size_t)(b0 + prow) * NFRAMES + 0) * 512 + pe4;
#pragma unroll
        for (int i = 0; i < 4; ++i) pfc[i] = cr0[i];
    }
    float pper = 0.f;
    if (t < RPW)
        pper = ld1f(f32, feats, (size_t)(b0 + t) * (NF * NFRAMES) + (NF - 1) * NFRAMES + 0);
    __syncthreads();

    const floatx4 z4 = {0.f, 0.f, 0.f, 0.f};
    int base = 0;
    for (int f = 0; f < NFRAMES; ++f) {
        if (t < RPW) period_s[t] = (int)rintf(pper);
        __syncthreads();
        if (t < RPW) {
            int fN = (f + 1 < NFRAMES) ? f + 1 : f;
            pper = ld1f(f32, feats, (size_t)(b0 + t) * (NF * NFRAMES) + (NF - 1) * NFRAMES + fN);
        }

        for (int kk = 0; kk < NSUB; ++kk) {
            // ================= BUILD (32 threads/row) =================
            {
                int row = prow;
                unsigned int* cat32 = (unsigned int*)catb;
                int cb = row * 212;
                int u0 = ps32 * 2;             // u32 index within 64-u32 feat2s block
                unsigned int o0 = cat32[cb + u0 + 0];
                unsigned int o1 = cat32[cb + u0 + 1];
                cat32[cb + 130 + u0 + 0] = o0;
                cat32[cb + 130 + u0 + 1] = o1;
                cat32[cb + u0 + 0] = packbf(pfc[0], pfc[1]);
                cat32[cb + u0 + 1] = packbf(pfc[2], pfc[3]);
                // prefetch next step's crow
                {
                    int sN = f * 4 + kk + 1;
                    if (sN > NFRAMES * 4 - 1) sN = NFRAMES * 4 - 1;
                    int fN = sN >> 2, kN = sN & 3;
                    const float* nc = cbuf + ((size_t)(b0 + row) * NFRAMES + fN) * 512
                                    + kN * 128 + pe4;
#pragma unroll
                    for (int i = 0; i < 4; ++i) pfc[i] = nc[i];
                }
                // lookback -> cat[192:260)
                int per = period_s[row];
#pragma unroll
                for (int ii = 0; ii < 3; ++ii) {
                    int i = ps32 * 3 + ii;
                    if (i < 68) {
                        int idx = LPREV - per + i - 2;
                        if (idx >= LPREV) idx -= per;
                        catb[row * 424 + 192 + i] = hist[row * 520 + ((base + idx) & 511)];
                    }
                }
            }
            __syncthreads();

            // ================= FW (tanh), 2 chains =================
            {
                floatx4 C0 = z4, C1 = z4;
#pragma unroll
                for (int kb = 0; kb < 13; ++kb) {
                    short8 a = ldA(catb, 212, ln, kb, lq);
                    if (kb & 1) C1 = mf(a, Bfw[kb], C1);
                    else        C0 = mf(a, Bfw[kb], C0);
                }
                float2 ca = selh(C0, h), cb2 = selh(C1, h);
                vpre[m0 * 72 + nj]       = f2bf(ftanh(ca.x + cb2.x));
                vpre[(m0 + 1) * 72 + nj] = f2bf(ftanh(ca.y + cb2.y));
            }
            __syncthreads();

            // ================= FWG (glu); also stage sv[0] =================
            {
                floatx4 C = z4;
#pragma unroll
                for (int kb = 0; kb < 2; ++kb)
                    C = mf(ldA(vpre, 36, ln, kb, lq), Bfwg[kb], C);
                float2 c = selh(C, h);
                float vpa = bf2f(vpre[m0 * 72 + nj]);
                float vpb = bf2f(vpre[(m0 + 1) * 72 + nj]);
                unsigned short oa = f2bf(vpa * fsig(c.x));
                unsigned short ob = f2bf(vpb * fsig(c.y));
                skx[m0 * 328 + 192 + nj] = oa;
                skx[(m0 + 1) * 328 + 192 + nj] = ob;
                xg [m0 * 200 + nj] = oa;
                xg [(m0 + 1) * 200 + nj] = ob;
                xg [m0 * 200 + 128 + nj]       = f2bf(svlo[0]);
                xg [(m0 + 1) * 200 + 128 + nj] = f2bf(svhi[0]);
            }
            __syncthreads();

            // ================= GRU + GLU x3 =================
#pragma unroll
            for (int G = 0; G < 3; ++G) {
                {
                    floatx4 Cr = z4, Cz = z4, Ci = z4, Ch = z4;
#pragma unroll
                    for (int kb = 0; kb < 6; ++kb) {
                        short8 a = ldA(xg, 100, ln, kb, lq);
                        Cr = mf(a, Br[G][kb], Cr);
                        Cz = mf(a, Bz[G][kb], Cz);
                        if (kb < 4) Ci = mf(a, Bi[G][kb], Ci);
                        else        Ch = mf(a, Bh[G][kb - 4], Ch);
                    }
                    float2 cr = selh(Cr, h), cz = selh(Cz, h);
                    float2 ci = selh(Ci, h), ch = selh(Ch, h);
                    {
                        float rr = fsig(cr.x), zz = fsig(cz.x);
                        float nn = ftanh(ci.x + rr * ch.x);
                        float sn = fmaf(zz, svlo[G] - nn, nn);
                        svlo[G] = sn;
                        svp[m0 * 72 + nj] = f2bf(sn);
                    }
                    {
                        float rr = fsig(cr.y), zz = fsig(cz.y);
                        float nn = ftanh(ci.y + rr * ch.y);
                        float sn = fmaf(zz, svhi[G] - nn, nn);
                        svhi[G] = sn;
                        svp[(m0 + 1) * 72 + nj] = f2bf(sn);
                    }
                }
                __syncthreads();
                {
                    floatx4 C = z4;
#pragma unroll
                    for (int kb = 0; kb < 2; ++kb)
                        C = mf(ldA(svp, 36, ln, kb, lq), Bg[G][kb], C);
                    float2 c = selh(C, h);
                    unsigned short oa = f2bf(svlo[G] * fsig(c.x));
                    unsigned short ob = f2bf(svhi[G] * fsig(c.y));
                    skx[m0 * 328 + G * 64 + nj] = oa;
                    skx[(m0 + 1) * 328 + G * 64 + nj] = ob;
                    if (G < 2) {
                        xg[m0 * 200 + nj] = oa;
                        xg[(m0 + 1) * 200 + nj] = ob;
                        xg[m0 * 200 + 128 + nj]       = f2bf(svlo[G + 1]);
                        xg[(m0 + 1) * 200 + 128 + nj] = f2bf(svhi[G + 1]);
                    }
                }
                __syncthreads();
            }

            // ================= SD (tanh), B from LDS, 4 chains =================
            {
                floatx4 C00 = z4, C01 = z4, C10 = z4, C11 = z4;
                int n0 = 32 * w + ln, n1 = n0 + 16;
#pragma unroll
                for (int kb = 0; kb < 10; ++kb) {
                    short8 a   = ldA(skx, 164, ln, kb, lq);
                    short8 b0f = ldA(wsd, 164, n0, kb, lq);
                    short8 b1f = ldA(wsd, 164, n1, kb, lq);
                    if (kb & 1) { C01 = mf(a, b0f, C01); C11 = mf(a, b1f, C11); }
                    else        { C00 = mf(a, b0f, C00); C10 = mf(a, b1f, C10); }
                }
                float2 a0 = selh(C00, h), a1 = selh(C01, h);
                float2 b0v = selh(C10, h), b1v = selh(C11, h);
                sdbb[m0 * 136 + n0]       = f2bf(ftanh(a0.x + a1.x));
                sdbb[(m0 + 1) * 136 + n0] = f2bf(ftanh(a0.y + a1.y));
                sdbb[m0 * 136 + n1]       = f2bf(ftanh(b0v.x + b1v.x));
                sdbb[(m0 + 1) * 136 + n1] = f2bf(ftanh(b0v.y + b1v.y));
            }
            __syncthreads();

            // ================= SG (glu) =================
            {
                floatx4 C0 = z4, C1 = z4;
                int n0 = 32 * w + ln, n1 = n0 + 16;
#pragma unroll
                for (int kb = 0; kb < 4; ++kb) {
                    short8 a = ldA(sdbb, 68, ln, kb, lq);
                    C0 = mf(a, Bsg[0][kb], C0);
                    C1 = mf(a, Bsg[1][kb], C1);
                }
                float2 c0 = selh(C0, h), c1 = selh(C1, h);
                float sa0 = bf2f(sdbb[m0 * 136 + n0]);
                float sa1 = bf2f(sdbb[(m0 + 1) * 136 + n0]);
                float sb0 = bf2f(sdbb[m0 * 136 + n1]);
                float sb1 = bf2f(sdbb[(m0 + 1) * 136 + n1]);
                sobb[m0 * 136 + n0]       = f2bf(sa0 * fsig(c0.x));
                sobb[(m0 + 1) * 136 + n0] = f2bf(sa1 * fsig(c0.y));
                sobb[m0 * 136 + n1]       = f2bf(sb0 * fsig(c1.x));
                sobb[(m0 + 1) * 136 + n1] = f2bf(sb1 * fsig(c1.y));
            }
            __syncthreads();

            // ================= OUT (tanh) + prev_sub fusion =================
            {
                floatx4 C = z4;
#pragma unroll
                for (int kb = 0; kb < 4; ++kb)
                    C = mf(ldA(sobb, 68, ln, kb, lq), Bout[kb], C);
                float2 c = selh(C, h);
#pragma unroll
                for (int r2 = 0; r2 < 2; ++r2) {
                    int m = m0 + r2;
                    float ov = ftanh(r2 ? c.y : c.x);
                    unsigned short ob = f2bf(ov);
                    hist[m * 520 + ((base + nj) & 511)] = ob;
                    catb[m * 424 + 128 + nj] = ob;
                    skx [m * 328 + 256 + nj] = ob;
                    xg  [m * 200 + 64  + nj] = ob;
                    size_t oi = (size_t)(b0 + m) * (NFRAMES * NSUB * SS)
                              + f * (NSUB * SS) + kk * SS + nj;
                    if (f32) ((float*)outp)[oi] = ov;
                    else     ((unsigned short*)outp)[oi] = ob;
                }
            }
            __syncthreads();

            base += SS;
        }
    }
}

// ---------- launch ----------
extern "C" void kernel_launch(void* const* d_in, const int* in_sizes, int n_in,
                              void* d_out, int out_size, void* d_ws, size_t ws_size,
                              hipStream_t stream) {
    const void* feats = d_in[0];
    const void* gfeat = d_in[1];
    const void* prev  = d_in[2];
    const void* Wc1   = d_in[3];
    const void* Wc2   = d_in[4];
    const void* Wc3   = d_in[5];
    const void* Wfw   = d_in[6];
    const void* Wfwg  = d_in[7];
    const void* Wih1  = d_in[8];
    const void* Whh1  = d_in[9];
    const void* Wih2  = d_in[10];
    const void* Whh2  = d_in[11];
    const void* Wih3  = d_in[12];
    const void* Whh3  = d_in[13];
    const void* Wg1   = d_in[14];
    const void* Wg2   = d_in[15];
    const void* Wg3   = d_in[16];
    const void* Wsg   = d_in[17];
    const void* Wsd   = d_in[18];
    const void* Wout  = d_in[19];

    int*          flag = (int*)d_ws;                                     // 1 int @ 0
    float*        cbuf = (float*)((char*)d_ws + 256);                    // 13,107,200 B
    unsigned int* wct  = (unsigned int*)((char*)d_ws + 256 + 13107200);  // 524,288 B
    uint4*        wbuf = (uint4*)((char*)d_ws + 256 + 13107200 + 524288);// 438,272 B

    fargan_detect<<<1, 1, 0, stream>>>(feats, flag);
    fargan_prep<<<(NFRAG + 255) / 256, 256, 0, stream>>>(flag, Wfw, Wfwg,
        Wih1, Whh1, Wih2, Whh2, Wih3, Whh3, Wg1, Wg2, Wg3, Wsg, Wsd, Wout, wbuf);
    fargan_prep_conv<<<512, 256, 0, stream>>>(flag, Wc1, Wc2, Wc3, wct);
    fargan_conv<<<BATCH * NFRAMES, 256, 0, stream>>>(feats, gfeat, flag, wct, cbuf);
    fargan_seq<<<BATCH / RPW, 512, 0, stream>>>(feats, prev, flag, cbuf, wbuf, d_out);
}

// Round 9
// 2827.949 us; speedup vs baseline: 2.0685x; 2.0685x over previous
//
#include <hip/hip_runtime.h>
#include <hip/hip_bf16.h>

// FARGAN vocoder on MI355X. Sizes fixed by the reference:
#define SS      64
#define NSUB    4
#define LPREV   512
#define NF      193
#define NFRAMES 100
#define BATCH   64
#define RPW     16     // batch rows per workgroup (MFMA M)

typedef __attribute__((ext_vector_type(8))) short   short8;   // 8 bf16 (4 VGPRs)
typedef __attribute__((ext_vector_type(4))) float   floatx4;  // MFMA C/D

// ---------- scalar helpers ----------
__device__ __forceinline__ float bf2f(unsigned short u) {
    return __uint_as_float(((unsigned int)u) << 16);
}
__device__ __forceinline__ unsigned short f2bf(float x) {
    unsigned int u = __float_as_uint(x);
    return (unsigned short)((u + 0x7fffu + ((u >> 16) & 1u)) >> 16);
}
__device__ __forceinline__ unsigned int packbf(float a, float b) {
    return (unsigned int)f2bf(a) | ((unsigned int)f2bf(b) << 16);
}
__device__ __forceinline__ float fexp2(float x) {
#if __has_builtin(__builtin_amdgcn_exp2f)
    return __builtin_amdgcn_exp2f(x);
#else
    return exp2f(x);
#endif
}
__device__ __forceinline__ float frcp(float x) {
#if __has_builtin(__builtin_amdgcn_rcpf)
    return __builtin_amdgcn_rcpf(x);
#else
    return 1.0f / x;
#endif
}
__device__ __forceinline__ float fsig(float x) {
    return frcp(1.0f + fexp2(-1.442695041f * x));
}
__device__ __forceinline__ float ftanh(float x) {
    return fmaf(2.0f, frcp(1.0f + fexp2(-2.885390082f * x)), -1.0f);
}
__device__ __forceinline__ float ld1f(int f32, const void* p, size_t i) {
    if (f32) return ((const float*)p)[i];
    return bf2f(((const unsigned short*)p)[i]);
}
__device__ __forceinline__ float lo16(unsigned int u) { return __uint_as_float(u << 16); }
__device__ __forceinline__ float hi16(unsigned int u) { return __uint_as_float(u & 0xffff0000u); }

// MFMA wrapper
__device__ __forceinline__ floatx4 mf(short8 a, short8 b, floatx4 c) {
    return __builtin_amdgcn_mfma_f32_16x16x32_bf16(a, b, c, 0, 0, 0);
}

// select this wave-half's two C rows (h is wave-uniform)
__device__ __forceinline__ float2 selh(const floatx4 C, int h) {
    float2 v;
    if (h) { v.x = C[2]; v.y = C[3]; }
    else   { v.x = C[0]; v.y = C[1]; }
    return v;
}

// A-fragment from packed-bf16 LDS buffer: row m, k-block kb, quad q.
__device__ __forceinline__ short8 ldA(const unsigned short* buf, int strideU,
                                      int m, int kb, int q) {
    const unsigned int* p = (const unsigned int*)buf + m * strideU + kb * 16 + q * 4;
    uint4 u = *(const uint4*)p;
    return __builtin_bit_cast(short8, u);
}
// B-fragment from prepacked weight buffer
__device__ __forceinline__ short8 ldB(const uint4* __restrict__ w, int idx) {
    return __builtin_bit_cast(short8, w[idx]);
}

// ---------- wbuf layout (units = 16B frags) ----------
#define OFF_FW   0        // 4t x 13kb
#define OFF_FWG  3328     // 4t x 2kb
#define OFF_GRU(G) (3840 + 4608*(G))   // r@+0(6kb) z@+1536(6kb) i@+3072(4kb) h@+4096(2kb)
#define OFF_WG(G)  (17664 + 512*(G))   // 4t x 2kb
#define OFF_SD   19200    // 8t x 10kb
#define OFF_SG   24320    // 8t x 4kb
#define OFF_OUT  26368    // 4t x 4kb
#define NFRAG    27392

// ---------- dtype detector ----------
__global__ void fargan_detect(const void* feats, int* flag) {
    const float* pf = (const float*)feats;
    int ok = 1;
    for (int f = 0; f < 50; ++f) {
        float v = pf[192 * NFRAMES + f];
        if (!(v >= 63.0f && v <= 301.0f)) { ok = 0; break; }
    }
    *flag = ok;
}

// ---------- weight prep: repack all seq weights into frag order ----------
__global__ __launch_bounds__(256) void fargan_prep(
    const int* __restrict__ flag,
    const void* Wfw, const void* Wfwg,
    const void* Wih1, const void* Whh1, const void* Wih2, const void* Whh2,
    const void* Wih3, const void* Whh3,
    const void* Wg1, const void* Wg2, const void* Wg3,
    const void* Wsg, const void* Wsd, const void* Wout,
    uint4* __restrict__ wbuf)
{
    int fi = blockIdx.x * 256 + threadIdx.x;
    if (fi >= NFRAG) return;
    int f32 = *flag;
    const void* mats[14] = {Wfw, Wfwg, Wih1, Whh1, Wih2, Whh2, Wih3, Whh3,
                            Wg1, Wg2, Wg3, Wsg, Wsd, Wout};
    const int NSEG = 20;
    const int sb[NSEG]  = {0,3328, 3840,5376,6912,7936, 8448,9984,11520,12544,
                           13056,14592,16128,17152, 17664,18176,18688, 19200,24320,26368};
    const int sa[NSEG]  = {0,1, 2,2,2,3, 4,4,4,5, 6,6,6,7, 8,9,10, 12,11,13};
    const int sbx[NSEG] = {-1,-1, 3,3,-1,-1, 5,5,-1,-1, 7,7,-1,-1, -1,-1,-1, -1,-1,-1};
    const int sro[NSEG] = {0,0, 0,64,128,128, 0,64,128,128, 0,64,128,128, 0,0,0, 0,0,0};
    const int skb[NSEG] = {13,2, 6,6,4,2, 6,6,4,2, 6,6,4,2, 2,2,2, 10,4,4};
    const int ska[NSEG] = {388,64, 128,128,128,64, 128,128,128,64, 128,128,128,64,
                           64,64,64, 320,128,128};
    const int skr[NSEG] = {388,64, 192,192,128,64, 192,192,128,64, 192,192,128,64,
                           64,64,64, 320,128,128};
    int s = 0;
    for (int i = 1; i < NSEG; ++i) if (fi >= sb[i]) s = i;
    int local = fi - sb[s];
    int ln = local & 15, lq = (local >> 4) & 3, tkb = local >> 6;
    int KB = skb[s];
    int kb = tkb % KB, tile = tkb / KB;
    int row = sro[s] + tile * 16 + ln;
    int Ka = ska[s], Kr = skr[s];
    union { unsigned short h[8]; uint4 v; } u;
#pragma unroll
    for (int j = 0; j < 8; ++j) {
        int k = kb * 32 + lq * 8 + j;
        unsigned short val = 0;
        if (k < Kr) {
            const void* m; size_t off;
            if (sbx[s] >= 0 && k >= Ka) { m = mats[sbx[s]]; off = (size_t)row * 64 + (k - Ka); }
            else                        { m = mats[sa[s]];  off = (size_t)row * Ka + k; }
            val = f32 ? f2bf(((const float*)m)[off]) : ((const unsigned short*)m)[off];
        }
        u.h[j] = val;
    }
    wbuf[fi] = u.v;
}

// ---------- prep: repack Wc1/2/3 transposed + bf16-pair packed ----------
__global__ __launch_bounds__(256) void fargan_prep_conv(
    const int* __restrict__ flag,
    const void* Wc1, const void* Wc2, const void* Wc3,
    unsigned int* __restrict__ wct)
{
    int idx = blockIdx.x * 256 + threadIdx.x;
    if (idx >= 131072) return;
    int f32 = *flag;
    const void* W; int n, k2;
    if (idx < 32768)      { W = Wc1; k2 = idx >> 8, n = idx & 255; }
    else if (idx < 65536) { W = Wc2; k2 = (idx - 32768) >> 8; n = idx & 255; }
    else                  { W = Wc3; k2 = (idx - 65536) >> 9; n = (idx - 65536) & 511; }
    size_t off = (size_t)n * 256 + 2 * k2;
    unsigned int v;
    if (f32) {
        const float* p = (const float*)W + off;
        v = packbf(p[0], p[1]);
    } else {
        v = *(const unsigned int*)((const unsigned short*)W + off);
    }
    wct[idx] = v;
}

// ---------- kernel 1: frame conv (coalesced transposed weights) ----------
template<bool F32>
__device__ __forceinline__ void conv_body(
    const void* __restrict__ feats, const void* __restrict__ gfeat,
    const unsigned int* __restrict__ wct, float* __restrict__ cbuf)
{
    int blk = blockIdx.x;
    int b = blk / NFRAMES, f = blk - b * NFRAMES;
    int t = threadIdx.x;
    __shared__ float xa[256], xb[256];

    float v;
    if (t < 192) v = ld1f(F32 ? 1 : 0, feats, (size_t)b * (NF * NFRAMES) + t * NFRAMES + f);
    else         v = ld1f(F32 ? 1 : 0, gfeat, (size_t)b * 64 + (t - 192));
    xa[t] = v;
    __syncthreads();

    const unsigned int* w1 = wct;
    const unsigned int* w2 = wct + 32768;
    const unsigned int* w3 = wct + 65536;

    float a0 = 0.f, a1 = 0.f;
#pragma unroll 8
    for (int k2 = 0; k2 < 128; ++k2) {
        unsigned int u = w1[k2 * 256 + t];
        a0 = fmaf(lo16(u), xa[2 * k2], a0);
        a1 = fmaf(hi16(u), xa[2 * k2 + 1], a1);
    }
    xb[t] = ftanh(a0 + a1);
    __syncthreads();

    a0 = 0.f; a1 = 0.f;
#pragma unroll 8
    for (int k2 = 0; k2 < 128; ++k2) {
        unsigned int u = w2[k2 * 256 + t];
        a0 = fmaf(lo16(u), xb[2 * k2], a0);
        a1 = fmaf(hi16(u), xb[2 * k2 + 1], a1);
    }
    xa[t] = ftanh(a0 + a1);
    __syncthreads();

    a0 = 0.f; a1 = 0.f;
    float b0 = 0.f, b1 = 0.f;
#pragma unroll 8
    for (int k2 = 0; k2 < 128; ++k2) {
        unsigned int u = w3[k2 * 512 + t];
        unsigned int u2 = w3[k2 * 512 + t + 256];
        a0 = fmaf(lo16(u),  xa[2 * k2],     a0);
        a1 = fmaf(hi16(u),  xa[2 * k2 + 1], a1);
        b0 = fmaf(lo16(u2), xa[2 * k2],     b0);
        b1 = fmaf(hi16(u2), xa[2 * k2 + 1], b1);
    }
    float* co = cbuf + ((size_t)b * NFRAMES + f) * 512;
    int e0 = t, e1 = t + 256;
    co[(e0 & 3) * 128 + (e0 >> 2)] = ftanh(a0 + a1);
    co[(e1 & 3) * 128 + (e1 >> 2)] = ftanh(b0 + b1);
}

__global__ __launch_bounds__(256) void fargan_conv(
    const void* feats, const void* gfeat,
    const int* flag, const unsigned int* wct, float* cbuf)
{
    if (*flag) conv_body<true>(feats, gfeat, wct, cbuf);
    else       conv_body<false>(feats, gfeat, wct, cbuf);
}

// ---------- kernel 2: sequential recurrence ----------
// 512 threads = 8 waves = 2/SIMD. Pair (w, h=w8>>2) on the same SIMD splits
// WORK: FW split-K (LDS partial), GRU gate-split (h0: r+i, h1: z+hh),
// SD/SG tile-split (full K in-lane), FWG/GLU redundant (tiny), OUT split-K.
// B-frags per wave ~44 uint4 -> fits 256-reg budget at 2 waves/SIMD.

__global__ __launch_bounds__(512, 2) void fargan_seq(
    const void* __restrict__ feats, const void* __restrict__ prev_in,
    const int* __restrict__ flag, const float* __restrict__ cbuf,
    const uint4* __restrict__ wbuf, void* __restrict__ outp)
{
    const int t = threadIdx.x;
    const int b0 = blockIdx.x * RPW;
    const int lane = t & 63, w8 = t >> 6;
    const int w = w8 & 3, h = w8 >> 2;
    const int lq = lane >> 4, ln = lane & 15;
    const int nj = 16 * w + ln;            // n for 64-wide layers
    const int m0 = 4 * lq + 2 * h;         // this wave's epilogue rows m0, m0+1
    const int f32 = *flag;

    // ---- LDS ----
    __shared__ __align__(16) unsigned short hist[RPW * 520];
    __shared__ __align__(16) unsigned short catb[RPW * 424];
    __shared__ __align__(16) unsigned short xg  [RPW * 200];
    __shared__ __align__(16) unsigned short skx [RPW * 328];
    __shared__ __align__(16) unsigned short sdbb[RPW * 136];
    __shared__ __align__(16) unsigned short sobb[RPW * 136];
    __shared__ __align__(16) unsigned short vpre[RPW * 72];
    __shared__ __align__(16) unsigned short svp [RPW * 72];
    __shared__ __align__(16) unsigned short wsd[128 * 328];
    __shared__ float part[4][16][68];      // phase partials / GRU gates (17.4 KB)
    __shared__ int period_s[RPW];

    // ---- resident B-fragments (per lane, HALF the set per wave) ----
    short8 Bfwg[2], Bga[3][6], Bgb[3][4], Bg[3][2], Bsg[4], Bout[2];
#pragma unroll
    for (int kb = 0; kb < 2; ++kb) Bfwg[kb] = ldB(wbuf, OFF_FWG + (w * 2 + kb) * 64 + lane);
#pragma unroll
    for (int G = 0; G < 3; ++G) {
        const int OA = OFF_GRU(G) + h * 1536;           // r (h=0) or z (h=1)
#pragma unroll
        for (int kb = 0; kb < 6; ++kb) Bga[G][kb] = ldB(wbuf, OA + (w * 6 + kb) * 64 + lane);
        if (h == 0) {
            const int OI = OFF_GRU(G) + 3072;
#pragma unroll
            for (int kb = 0; kb < 4; ++kb) Bgb[G][kb] = ldB(wbuf, OI + (w * 4 + kb) * 64 + lane);
        } else {
            const int OH = OFF_GRU(G) + 4096;
#pragma unroll
            for (int kb = 0; kb < 2; ++kb) Bgb[G][kb] = ldB(wbuf, OH + (w * 2 + kb) * 64 + lane);
        }
#pragma unroll
        for (int kb = 0; kb < 2; ++kb) Bg[G][kb] = ldB(wbuf, OFF_WG(G) + (w * 2 + kb) * 64 + lane);
    }
#pragma unroll
    for (int kb = 0; kb < 4; ++kb)
        Bsg[kb] = ldB(wbuf, OFF_SG + ((2 * w + h) * 4 + kb) * 64 + lane);
#pragma unroll
    for (int j = 0; j < 2; ++j)
        Bout[j] = ldB(wbuf, OFF_OUT + (w * 4 + (2 * j + h)) * 64 + lane);

    // ---- Wsd -> LDS from wbuf ----
    for (int fi = t; fi < 8 * 10 * 64; fi += 512) {
        int lane2 = fi & 63, tkb = fi >> 6;
        int kb = tkb % 10, tile = tkb / 10;
        int lq2 = lane2 >> 4, ln2 = lane2 & 15;
        int row = tile * 16 + ln2;
        uint4 v = wbuf[OFF_SD + fi];
        *(uint4*)((unsigned int*)wsd + row * 164 + kb * 16 + lq2 * 4) = v;
    }

    // ---- zero init LDS state + hist fill ----
    for (int i = t; i < RPW * 424; i += 512) catb[i] = 0;
    for (int i = t; i < RPW * 200; i += 512) xg[i] = 0;
    for (int i = t; i < RPW * 328; i += 512) skx[i] = 0;
    for (int i = t; i < RPW * 136; i += 512) { sdbb[i] = 0; sobb[i] = 0; }
    for (int i = t; i < RPW * 72;  i += 512) { vpre[i] = 0; svp[i] = 0; }
    for (int i = t; i < RPW * 512; i += 512) {
        int row = i >> 9, c = i & 511;
        hist[row * 520 + c] = f2bf(ld1f(f32, prev_in, (size_t)(b0 + row) * LPREV + c));
    }
    __syncthreads();
    for (int i = t; i < RPW * 64; i += 512) {
        int row = i >> 6, c = i & 63;
        unsigned short hh = hist[row * 520 + 448 + c];
        catb[row * 424 + 128 + c] = hh;
        skx [row * 328 + 256 + c] = hh;
        xg  [row * 200 + 64  + c] = hh;
    }

    // GRU states: this wave's two rows (m0, m0+1), col nj
    float svlo[3] = {0.f, 0.f, 0.f}, svhi[3] = {0.f, 0.f, 0.f};

    // ---- prefetch regs (32 threads/row) ----
    const int prow = t >> 5, ps32 = t & 31, pe4 = (t & 31) * 4;
    float pfc[4];
    {
        const float* cr0 = cbuf + ((size_t)(b0 + prow) * NFRAMES + 0) * 512 + pe4;
#pragma unroll
        for (int i = 0; i < 4; ++i) pfc[i] = cr0[i];
    }
    float pper = 0.f;
    if (t < RPW)
        pper = ld1f(f32, feats, (size_t)(b0 + t) * (NF * NFRAMES) + (NF - 1) * NFRAMES + 0);
    __syncthreads();

    const int nkb_fw = h ? 6 : 7;          // FW k-blocks: h=0 -> 0..6, h=1 -> 7..12
    const floatx4 z4 = {0.f, 0.f, 0.f, 0.f};
    int base = 0;
    for (int f = 0; f < NFRAMES; ++f) {
        if (t < RPW) period_s[t] = (int)rintf(pper);
        __syncthreads();
        if (t < RPW) {
            int fN = (f + 1 < NFRAMES) ? f + 1 : f;
            pper = ld1f(f32, feats, (size_t)(b0 + t) * (NF * NFRAMES) + (NF - 1) * NFRAMES + fN);
        }

        for (int kk = 0; kk < NSUB; ++kk) {
            // FW B-frags streamed from L2 each step (issued early, used in FW)
            short8 Bfw[7];
#pragma unroll
            for (int j = 0; j < 7; ++j)
                if (j < nkb_fw)
                    Bfw[j] = ldB(wbuf, OFF_FW + (w * 13 + (h ? 7 + j : j)) * 64 + lane);

            // ================= BUILD (32 threads/row) =================
            {
                int row = prow;
                unsigned int* cat32 = (unsigned int*)catb;
                int cb = row * 212;
                int u0 = ps32 * 2;
                unsigned int o0 = cat32[cb + u0 + 0];
                unsigned int o1 = cat32[cb + u0 + 1];
                cat32[cb + 130 + u0 + 0] = o0;
                cat32[cb + 130 + u0 + 1] = o1;
                cat32[cb + u0 + 0] = packbf(pfc[0], pfc[1]);
                cat32[cb + u0 + 1] = packbf(pfc[2], pfc[3]);
                {
                    int sN = f * 4 + kk + 1;
                    if (sN > NFRAMES * 4 - 1) sN = NFRAMES * 4 - 1;
                    int fN = sN >> 2, kN = sN & 3;
                    const float* nc = cbuf + ((size_t)(b0 + row) * NFRAMES + fN) * 512
                                    + kN * 128 + pe4;
#pragma unroll
                    for (int i = 0; i < 4; ++i) pfc[i] = nc[i];
                }
                int per = period_s[row];
#pragma unroll
                for (int ii = 0; ii < 3; ++ii) {
                    int i = ps32 * 3 + ii;
                    if (i < 68) {
                        int idx = LPREV - per + i - 2;
                        if (idx >= LPREV) idx -= per;
                        catb[row * 424 + 192 + i] = hist[row * 520 + ((base + idx) & 511)];
                    }
                }
            }
            __syncthreads();                                   // A

            // ================= FW: split-K MFMA -> partials =================
            {
                floatx4 C0 = z4, C1 = z4;
#pragma unroll
                for (int j = 0; j < 7; ++j)
                    if (j < nkb_fw) {
                        short8 a = ldA(catb, 212, ln, (h ? 7 + j : j), lq);
                        if (j & 1) C1 = mf(a, Bfw[j], C1);
                        else       C0 = mf(a, Bfw[j], C0);
                    }
#pragma unroll
                for (int r = 0; r < 4; ++r) part[h][4 * lq + r][nj] = C0[r] + C1[r];
            }
            __syncthreads();                                   // B

            // ================= FW epilogue =================
#pragma unroll
            for (int r2 = 0; r2 < 2; ++r2) {
                int m = m0 + r2;
                vpre[m * 72 + nj] = f2bf(ftanh(part[0][m][nj] + part[1][m][nj]));
            }
            __syncthreads();                                   // C

            // ================= FWG (redundant) =================
            {
                floatx4 C = z4;
#pragma unroll
                for (int kb = 0; kb < 2; ++kb)
                    C = mf(ldA(vpre, 36, ln, kb, lq), Bfwg[kb], C);
                float2 c = selh(C, h);
                float vpa = bf2f(vpre[m0 * 72 + nj]);
                float vpb = bf2f(vpre[(m0 + 1) * 72 + nj]);
                unsigned short oa = f2bf(vpa * fsig(c.x));
                unsigned short ob = f2bf(vpb * fsig(c.y));
                skx[m0 * 328 + 192 + nj] = oa;
                skx[(m0 + 1) * 328 + 192 + nj] = ob;
                xg [m0 * 200 + nj] = oa;
                xg [(m0 + 1) * 200 + nj] = ob;
                xg [m0 * 200 + 128 + nj]       = f2bf(svlo[0]);
                xg [(m0 + 1) * 200 + 128 + nj] = f2bf(svhi[0]);
            }
            __syncthreads();                                   // D

            // ================= GRU + GLU x3 =================
#pragma unroll
            for (int G = 0; G < 3; ++G) {
                // gate-split MFMA: h=0 -> r+i ; h=1 -> z+hh
                {
                    floatx4 Ca = z4, Cb = z4;
                    if (h == 0) {
#pragma unroll
                        for (int kb = 0; kb < 6; ++kb) {
                            short8 a = ldA(xg, 100, ln, kb, lq);
                            Ca = mf(a, Bga[G][kb], Ca);
                            if (kb < 4) Cb = mf(a, Bgb[G][kb], Cb);
                        }
                    } else {
#pragma unroll
                        for (int kb = 0; kb < 6; ++kb) {
                            short8 a = ldA(xg, 100, ln, kb, lq);
                            Ca = mf(a, Bga[G][kb], Ca);
                            if (kb >= 4) Cb = mf(a, Bgb[G][kb - 4], Cb);
                        }
                    }
#pragma unroll
                    for (int r = 0; r < 4; ++r) {
                        part[h][4 * lq + r][nj]     = Ca[r];   // r or z
                        part[2 + h][4 * lq + r][nj] = Cb[r];   // i or hh
                    }
                }
                __syncthreads();                               // E

                // GRU epilogue (h-split rows)
#pragma unroll
                for (int r2 = 0; r2 < 2; ++r2) {
                    int m = m0 + r2;
                    float rr = fsig(part[0][m][nj]);
                    float zz = fsig(part[1][m][nj]);
                    float nn = ftanh(part[2][m][nj] + rr * part[3][m][nj]);
                    float sold = r2 ? svhi[G] : svlo[G];
                    float sn = fmaf(zz, sold - nn, nn);
                    if (r2) svhi[G] = sn; else svlo[G] = sn;
                    svp[m * 72 + nj] = f2bf(sn);
                }
                __syncthreads();                               // F

                // GLU (redundant)
                {
                    floatx4 C = z4;
#pragma unroll
                    for (int kb = 0; kb < 2; ++kb)
                        C = mf(ldA(svp, 36, ln, kb, lq), Bg[G][kb], C);
                    float2 c = selh(C, h);
                    unsigned short oa = f2bf(svlo[G] * fsig(c.x));
                    unsigned short ob = f2bf(svhi[G] * fsig(c.y));
                    skx[m0 * 328 + G * 64 + nj] = oa;
                    skx[(m0 + 1) * 328 + G * 64 + nj] = ob;
                    if (G < 2) {
                        xg[m0 * 200 + nj] = oa;
                        xg[(m0 + 1) * 200 + nj] = ob;
                        xg[m0 * 200 + 128 + nj]       = f2bf(svlo[G + 1]);
                        xg[(m0 + 1) * 200 + 128 + nj] = f2bf(svhi[G + 1]);
                    }
                }
                __syncthreads();                               // G
            }

            // ================= SD: tile-split, full K, in-lane =================
            {
                int n = (2 * w + h) * 16 + ln;
                floatx4 C0 = z4, C1 = z4;
#pragma unroll
                for (int kb = 0; kb < 10; ++kb) {
                    short8 a = ldA(skx, 164, ln, kb, lq);
                    short8 b = ldA(wsd, 164, n, kb, lq);
                    if (kb & 1) C1 = mf(a, b, C1);
                    else        C0 = mf(a, b, C0);
                }
#pragma unroll
                for (int r = 0; r < 4; ++r)
                    sdbb[(4 * lq + r) * 136 + n] = f2bf(ftanh(C0[r] + C1[r]));
            }
            __syncthreads();                                   // H

            // ================= SG: tile-split =================
            {
                int n = (2 * w + h) * 16 + ln;
                floatx4 C = z4;
#pragma unroll
                for (int kb = 0; kb < 4; ++kb)
                    C = mf(ldA(sdbb, 68, ln, kb, lq), Bsg[kb], C);
#pragma unroll
                for (int r = 0; r < 4; ++r) {
                    int m = 4 * lq + r;
                    float s = bf2f(sdbb[m * 136 + n]);
                    sobb[m * 136 + n] = f2bf(s * fsig(C[r]));
                }
            }
            __syncthreads();                                   // I

            // ================= OUT: split-K MFMA -> partials =================
            {
                floatx4 C = z4;
                C = mf(ldA(sobb, 68, ln, h, lq),     Bout[0], C);
                C = mf(ldA(sobb, 68, ln, 2 + h, lq), Bout[1], C);
#pragma unroll
                for (int r = 0; r < 4; ++r) part[h][4 * lq + r][nj] = C[r];
            }
            __syncthreads();                                   // J

            // ================= OUT epilogue + prev_sub fusion =================
#pragma unroll
            for (int r2 = 0; r2 < 2; ++r2) {
                int m = m0 + r2;
                float ov = ftanh(part[0][m][nj] + part[1][m][nj]);
                unsigned short ob = f2bf(ov);
                hist[m * 520 + ((base + nj) & 511)] = ob;
                catb[m * 424 + 128 + nj] = ob;
                skx [m * 328 + 256 + nj] = ob;
                xg  [m * 200 + 64  + nj] = ob;
                size_t oi = (size_t)(b0 + m) * (NFRAMES * NSUB * SS)
                          + f * (NSUB * SS) + kk * SS + nj;
                if (f32) ((float*)outp)[oi] = ov;
                else     ((unsigned short*)outp)[oi] = ob;
            }
            __syncthreads();                                   // K

            base += SS;
        }
    }
}

// ---------- launch ----------
extern "C" void kernel_launch(void* const* d_in, const int* in_sizes, int n_in,
                              void* d_out, int out_size, void* d_ws, size_t ws_size,
                              hipStream_t stream) {
    const void* feats = d_in[0];
    const void* gfeat = d_in[1];
    const void* prev  = d_in[2];
    const void* Wc1   = d_in[3];
    const void* Wc2   = d_in[4];
    const void* Wc3   = d_in[5];
    const void* Wfw   = d_in[6];
    const void* Wfwg  = d_in[7];
    const void* Wih1  = d_in[8];
    const void* Whh1  = d_in[9];
    const void* Wih2  = d_in[10];
    const void* Whh2  = d_in[11];
    const void* Wih3  = d_in[12];
    const void* Whh3  = d_in[13];
    const void* Wg1   = d_in[14];
    const void* Wg2   = d_in[15];
    const void* Wg3   = d_in[16];
    const void* Wsg   = d_in[17];
    const void* Wsd   = d_in[18];
    const void* Wout  = d_in[19];

    int*          flag = (int*)d_ws;                                     // 1 int @ 0
    float*        cbuf = (float*)((char*)d_ws + 256);                    // 13,107,200 B
    unsigned int* wct  = (unsigned int*)((char*)d_ws + 256 + 13107200);  // 524,288 B
    uint4*        wbuf = (uint4*)((char*)d_ws + 256 + 13107200 + 524288);// 438,272 B

    fargan_detect<<<1, 1, 0, stream>>>(feats, flag);
    fargan_prep<<<(NFRAG + 255) / 256, 256, 0, stream>>>(flag, Wfw, Wfwg,
        Wih1, Whh1, Wih2, Whh2, Wih3, Whh3, Wg1, Wg2, Wg3, Wsg, Wsd, Wout, wbuf);
    fargan_prep_conv<<<512, 256, 0, stream>>>(flag, Wc1, Wc2, Wc3, wct);
    fargan_conv<<<BATCH * NFRAMES, 256, 0, stream>>>(feats, gfeat, flag, wct, cbuf);
    fargan_seq<<<BATCH / RPW, 512, 0, stream>>>(feats, prev, flag, cbuf, wbuf, d_out);
}

// Round 10
// 2680.358 us; speedup vs baseline: 2.1824x; 1.0551x over previous
//
#include <hip/hip_runtime.h>
#include <hip/hip_bf16.h>

// FARGAN vocoder on MI355X. Sizes fixed by the reference:
#define SS      64
#define NSUB    4
#define LPREV   512
#define NF      193
#define NFRAMES 100
#define BATCH   64
#define RPW     16     // batch rows per workgroup (MFMA M)

typedef __attribute__((ext_vector_type(8))) short   short8;   // 8 bf16 (4 VGPRs)
typedef __attribute__((ext_vector_type(4))) float   floatx4;  // MFMA C/D

// ---------- scalar helpers ----------
__device__ __forceinline__ float bf2f(unsigned short u) {
    return __uint_as_float(((unsigned int)u) << 16);
}
__device__ __forceinline__ unsigned short f2bf(float x) {
    unsigned int u = __float_as_uint(x);
    return (unsigned short)((u + 0x7fffu + ((u >> 16) & 1u)) >> 16);
}
__device__ __forceinline__ unsigned int packbf(float a, float b) {
    return (unsigned int)f2bf(a) | ((unsigned int)f2bf(b) << 16);
}
__device__ __forceinline__ float fexp2(float x) {
#if __has_builtin(__builtin_amdgcn_exp2f)
    return __builtin_amdgcn_exp2f(x);
#else
    return exp2f(x);
#endif
}
__device__ __forceinline__ float frcp(float x) {
#if __has_builtin(__builtin_amdgcn_rcpf)
    return __builtin_amdgcn_rcpf(x);
#else
    return 1.0f / x;
#endif
}
__device__ __forceinline__ float fsig(float x) {
    return frcp(1.0f + fexp2(-1.442695041f * x));
}
__device__ __forceinline__ float ftanh(float x) {
    return fmaf(2.0f, frcp(1.0f + fexp2(-2.885390082f * x)), -1.0f);
}
__device__ __forceinline__ float ld1f(int f32, const void* p, size_t i) {
    if (f32) return ((const float*)p)[i];
    return bf2f(((const unsigned short*)p)[i]);
}
__device__ __forceinline__ float lo16(unsigned int u) { return __uint_as_float(u << 16); }
__device__ __forceinline__ float hi16(unsigned int u) { return __uint_as_float(u & 0xffff0000u); }

// MFMA wrapper
__device__ __forceinline__ floatx4 mf(short8 a, short8 b, floatx4 c) {
    return __builtin_amdgcn_mfma_f32_16x16x32_bf16(a, b, c, 0, 0, 0);
}

// A-fragment from packed-bf16 LDS buffer: row m, k-block kb, quad q.
__device__ __forceinline__ short8 ldA(const unsigned short* buf, int strideU,
                                      int m, int kb, int q) {
    const unsigned int* p = (const unsigned int*)buf + m * strideU + kb * 16 + q * 4;
    uint4 u = *(const uint4*)p;
    return __builtin_bit_cast(short8, u);
}
// B-fragment from prepacked weight buffer
__device__ __forceinline__ short8 ldB(const uint4* __restrict__ w, int idx) {
    return __builtin_bit_cast(short8, w[idx]);
}

// ---------- wbuf layout (units = 16B frags) ----------
#define OFF_FW   0        // 4t x 13kb
#define OFF_FWG  3328     // 4t x 2kb
#define OFF_GRU(G) (3840 + 4608*(G))   // r@+0(6kb) z@+1536(6kb) i@+3072(4kb) h@+4096(2kb)
#define OFF_WG(G)  (17664 + 512*(G))   // 4t x 2kb
#define OFF_SD   19200    // 8t x 10kb
#define OFF_SG   24320    // 8t x 4kb
#define OFF_OUT  26368    // 4t x 4kb
#define NFRAG    27392

// ---------- dtype detector ----------
__global__ void fargan_detect(const void* feats, int* flag) {
    const float* pf = (const float*)feats;
    int ok = 1;
    for (int f = 0; f < 50; ++f) {
        float v = pf[192 * NFRAMES + f];
        if (!(v >= 63.0f && v <= 301.0f)) { ok = 0; break; }
    }
    *flag = ok;
}

// ---------- weight prep: repack all seq weights into frag order ----------
__global__ __launch_bounds__(256) void fargan_prep(
    const int* __restrict__ flag,
    const void* Wfw, const void* Wfwg,
    const void* Wih1, const void* Whh1, const void* Wih2, const void* Whh2,
    const void* Wih3, const void* Whh3,
    const void* Wg1, const void* Wg2, const void* Wg3,
    const void* Wsg, const void* Wsd, const void* Wout,
    uint4* __restrict__ wbuf)
{
    int fi = blockIdx.x * 256 + threadIdx.x;
    if (fi >= NFRAG) return;
    int f32 = *flag;
    const void* mats[14] = {Wfw, Wfwg, Wih1, Whh1, Wih2, Whh2, Wih3, Whh3,
                            Wg1, Wg2, Wg3, Wsg, Wsd, Wout};
    const int NSEG = 20;
    const int sb[NSEG]  = {0,3328, 3840,5376,6912,7936, 8448,9984,11520,12544,
                           13056,14592,16128,17152, 17664,18176,18688, 19200,24320,26368};
    const int sa[NSEG]  = {0,1, 2,2,2,3, 4,4,4,5, 6,6,6,7, 8,9,10, 12,11,13};
    const int sbx[NSEG] = {-1,-1, 3,3,-1,-1, 5,5,-1,-1, 7,7,-1,-1, -1,-1,-1, -1,-1,-1};
    const int sro[NSEG] = {0,0, 0,64,128,128, 0,64,128,128, 0,64,128,128, 0,0,0, 0,0,0};
    const int skb[NSEG] = {13,2, 6,6,4,2, 6,6,4,2, 6,6,4,2, 2,2,2, 10,4,4};
    const int ska[NSEG] = {388,64, 128,128,128,64, 128,128,128,64, 128,128,128,64,
                           64,64,64, 320,128,128};
    const int skr[NSEG] = {388,64, 192,192,128,64, 192,192,128,64, 192,192,128,64,
                           64,64,64, 320,128,128};
    int s = 0;
    for (int i = 1; i < NSEG; ++i) if (fi >= sb[i]) s = i;
    int local = fi - sb[s];
    int ln = local & 15, lq = (local >> 4) & 3, tkb = local >> 6;
    int KB = skb[s];
    int kb = tkb % KB, tile = tkb / KB;
    int row = sro[s] + tile * 16 + ln;
    int Ka = ska[s], Kr = skr[s];
    union { unsigned short h[8]; uint4 v; } u;
#pragma unroll
    for (int j = 0; j < 8; ++j) {
        int k = kb * 32 + lq * 8 + j;
        unsigned short val = 0;
        if (k < Kr) {
            const void* m; size_t off;
            if (sbx[s] >= 0 && k >= Ka) { m = mats[sbx[s]]; off = (size_t)row * 64 + (k - Ka); }
            else                        { m = mats[sa[s]];  off = (size_t)row * Ka + k; }
            val = f32 ? f2bf(((const float*)m)[off]) : ((const unsigned short*)m)[off];
        }
        u.h[j] = val;
    }
    wbuf[fi] = u.v;
}

// ---------- prep: repack Wc1/2/3 transposed + bf16-pair packed ----------
__global__ __launch_bounds__(256) void fargan_prep_conv(
    const int* __restrict__ flag,
    const void* Wc1, const void* Wc2, const void* Wc3,
    unsigned int* __restrict__ wct)
{
    int idx = blockIdx.x * 256 + threadIdx.x;
    if (idx >= 131072) return;
    int f32 = *flag;
    const void* W; int n, k2;
    if (idx < 32768)      { W = Wc1; k2 = idx >> 8, n = idx & 255; }
    else if (idx < 65536) { W = Wc2; k2 = (idx - 32768) >> 8; n = idx & 255; }
    else                  { W = Wc3; k2 = (idx - 65536) >> 9; n = (idx - 65536) & 511; }
    size_t off = (size_t)n * 256 + 2 * k2;
    unsigned int v;
    if (f32) {
        const float* p = (const float*)W + off;
        v = packbf(p[0], p[1]);
    } else {
        v = *(const unsigned int*)((const unsigned short*)W + off);
    }
    wct[idx] = v;
}

// ---------- kernel 1: frame conv -> bf16 output cb16[b][f][k*128+j] ----------
template<bool F32>
__device__ __forceinline__ void conv_body(
    const void* __restrict__ feats, const void* __restrict__ gfeat,
    const unsigned int* __restrict__ wct, unsigned short* __restrict__ cb16)
{
    int blk = blockIdx.x;
    int b = blk / NFRAMES, f = blk - b * NFRAMES;
    int t = threadIdx.x;
    __shared__ float xa[256], xb[256];

    float v;
    if (t < 192) v = ld1f(F32 ? 1 : 0, feats, (size_t)b * (NF * NFRAMES) + t * NFRAMES + f);
    else         v = ld1f(F32 ? 1 : 0, gfeat, (size_t)b * 64 + (t - 192));
    xa[t] = v;
    __syncthreads();

    const unsigned int* w1 = wct;
    const unsigned int* w2 = wct + 32768;
    const unsigned int* w3 = wct + 65536;

    float a0 = 0.f, a1 = 0.f;
#pragma unroll 8
    for (int k2 = 0; k2 < 128; ++k2) {
        unsigned int u = w1[k2 * 256 + t];
        a0 = fmaf(lo16(u), xa[2 * k2], a0);
        a1 = fmaf(hi16(u), xa[2 * k2 + 1], a1);
    }
    xb[t] = ftanh(a0 + a1);
    __syncthreads();

    a0 = 0.f; a1 = 0.f;
#pragma unroll 8
    for (int k2 = 0; k2 < 128; ++k2) {
        unsigned int u = w2[k2 * 256 + t];
        a0 = fmaf(lo16(u), xb[2 * k2], a0);
        a1 = fmaf(hi16(u), xb[2 * k2 + 1], a1);
    }
    xa[t] = ftanh(a0 + a1);
    __syncthreads();

    a0 = 0.f; a1 = 0.f;
    float b0 = 0.f, b1 = 0.f;
#pragma unroll 8
    for (int k2 = 0; k2 < 128; ++k2) {
        unsigned int u = w3[k2 * 512 + t];
        unsigned int u2 = w3[k2 * 512 + t + 256];
        a0 = fmaf(lo16(u),  xa[2 * k2],     a0);
        a1 = fmaf(hi16(u),  xa[2 * k2 + 1], a1);
        b0 = fmaf(lo16(u2), xa[2 * k2],     b0);
        b1 = fmaf(hi16(u2), xa[2 * k2 + 1], b1);
    }
    unsigned short* co = cb16 + ((size_t)b * NFRAMES + f) * 512;
    // element e (= j*4+k) -> co[k*128 + j], bf16
    int e0 = t, e1 = t + 256;
    co[(e0 & 3) * 128 + (e0 >> 2)] = f2bf(ftanh(a0 + a1));
    co[(e1 & 3) * 128 + (e1 >> 2)] = f2bf(ftanh(b0 + b1));
}

__global__ __launch_bounds__(256) void fargan_conv(
    const void* feats, const void* gfeat,
    const int* flag, const unsigned int* wct, unsigned short* cb16)
{
    if (*flag) conv_body<true>(feats, gfeat, wct, cb16);
    else       conv_body<false>(feats, gfeat, wct, cb16);
}

// ---------- kernel 2: sequential recurrence (R7 structure, vm-free steps) ----------
// 4 WGs x 16 rows, 4 waves n-split, resident weights. All global I/O batched
// per frame: cframe LDS staging (load), hist-ring flush (store). Steady-state
// steps touch no global memory -> barrier drains are lgkm-only.

__global__ __launch_bounds__(256, 1) void fargan_seq(
    const void* __restrict__ feats, const void* __restrict__ prev_in,
    const int* __restrict__ flag, const unsigned short* __restrict__ cb16,
    const uint4* __restrict__ wbuf, void* __restrict__ outp)
{
    const int t = threadIdx.x;
    const int b0 = blockIdx.x * RPW;
    const int lane = t & 63, w = t >> 6;
    const int lq = lane >> 4, ln = lane & 15;
    const int nj = 16 * w + ln;            // n for 64-wide layers
    const int f32 = *flag;

    // ---- LDS (158.8 KB total) ----
    __shared__ __align__(16) unsigned short hist[RPW * 520];   // bf16 ring mod-512
    __shared__ __align__(16) unsigned short catb[RPW * 424];   // [feat2s|ps|look|sfw|pad]
    __shared__ __align__(16) unsigned short xg  [RPW * 200];   // [in0|ps|s]
    __shared__ __align__(16) unsigned short skx [RPW * 328];   // [o1|o2|o3|fw|ps]
    __shared__ __align__(16) unsigned short sdbb[RPW * 136];
    __shared__ __align__(16) unsigned short sobb[RPW * 136];
    __shared__ __align__(16) unsigned short v64 [RPW * 72];    // vpre / svp (shared)
    __shared__ __align__(16) unsigned short wsd[128 * 328];    // Wsd, 164u stride
    __shared__ __align__(16) unsigned int   cframe[RPW * 260]; // frame feat2s, bf16 pairs
    __shared__ int period_s[RPW];

    // ---- resident B-fragments, coalesced preload from wbuf ----
    short8 Bfw[13], Bfwg[2], Bout[4];
    short8 Br[3][6], Bz[3][6], Bi[3][4], Bh[3][2], Bg[3][2];
    short8 Bsg[2][4];
#pragma unroll
    for (int kb = 0; kb < 13; ++kb) Bfw[kb] = ldB(wbuf, OFF_FW + (w * 13 + kb) * 64 + lane);
#pragma unroll
    for (int kb = 0; kb < 2; ++kb)  Bfwg[kb] = ldB(wbuf, OFF_FWG + (w * 2 + kb) * 64 + lane);
#pragma unroll
    for (int G = 0; G < 3; ++G) {
        const int OR = OFF_GRU(G), OZ = OR + 1536, OI = OR + 3072, OH = OR + 4096;
#pragma unroll
        for (int kb = 0; kb < 6; ++kb) {
            Br[G][kb] = ldB(wbuf, OR + (w * 6 + kb) * 64 + lane);
            Bz[G][kb] = ldB(wbuf, OZ + (w * 6 + kb) * 64 + lane);
        }
#pragma unroll
        for (int kb = 0; kb < 4; ++kb) Bi[G][kb] = ldB(wbuf, OI + (w * 4 + kb) * 64 + lane);
#pragma unroll
        for (int kb = 0; kb < 2; ++kb) {
            Bh[G][kb] = ldB(wbuf, OH + (w * 2 + kb) * 64 + lane);
            Bg[G][kb] = ldB(wbuf, OFF_WG(G) + (w * 2 + kb) * 64 + lane);
        }
    }
#pragma unroll
    for (int tile = 0; tile < 2; ++tile)
#pragma unroll
        for (int kb = 0; kb < 4; ++kb)
            Bsg[tile][kb] = ldB(wbuf, OFF_SG + ((2 * w + tile) * 4 + kb) * 64 + lane);
#pragma unroll
    for (int kb = 0; kb < 4; ++kb) Bout[kb] = ldB(wbuf, OFF_OUT + (w * 4 + kb) * 64 + lane);

    // ---- Wsd -> LDS from wbuf ----
    for (int fi = t; fi < 8 * 10 * 64; fi += 256) {
        int lane2 = fi & 63, tkb = fi >> 6;
        int kb = tkb % 10, tile = tkb / 10;
        int lq2 = lane2 >> 4, ln2 = lane2 & 15;
        int row = tile * 16 + ln2;
        uint4 v = wbuf[OFF_SD + fi];
        *(uint4*)((unsigned int*)wsd + row * 164 + kb * 16 + lq2 * 4) = v;
    }

    // ---- zero init LDS state + hist fill ----
    for (int i = t; i < RPW * 424; i += 256) catb[i] = 0;
    for (int i = t; i < RPW * 200; i += 256) xg[i] = 0;
    for (int i = t; i < RPW * 328; i += 256) skx[i] = 0;
    for (int i = t; i < RPW * 136; i += 256) { sdbb[i] = 0; sobb[i] = 0; }
    for (int i = t; i < RPW * 72;  i += 256) v64[i] = 0;
    for (int i = t; i < RPW * 260; i += 256) cframe[i] = 0;
    for (int i = t; i < RPW * 512; i += 256) {
        int row = i >> 9, c = i & 511;
        hist[row * 520 + c] = f2bf(ld1f(f32, prev_in, (size_t)(b0 + row) * LPREV + c));
    }
    __syncthreads();
    // initial prev_sub slots (step 0)
    for (int i = t; i < RPW * 64; i += 256) {
        int row = i >> 6, c = i & 63;
        unsigned short hh = hist[row * 520 + 448 + c];
        catb[row * 424 + 128 + c] = hh;
        skx [row * 328 + 256 + c] = hh;
        xg  [row * 200 + 64  + c] = hh;
    }

    // GRU states in C-layout registers: svr[G][r] = s[row 4lq+r][col nj]
    floatx4 svr[3];
#pragma unroll
    for (int G = 0; G < 3; ++G) svr[G] = (floatx4){0.f, 0.f, 0.f, 0.f};
    __syncthreads();

    const floatx4 z4 = {0.f, 0.f, 0.f, 0.f};
    int base = 0;
    for (int f = 0; f < NFRAMES; ++f) {
        // ---- frame top: kk=0 sfw <- old cframe[3]; then load new frame ----
        for (int i = t; i < RPW * 64; i += 256) {
            int row = i >> 6, j = i & 63;
            ((unsigned int*)catb)[row * 212 + 130 + j] = cframe[row * 260 + 192 + j];
        }
        __syncthreads();                                       // F1
        {
            int row = t >> 4, part = t & 15;
            const uint4* src = (const uint4*)(cb16 + ((size_t)(b0 + row) * NFRAMES + f) * 512)
                             + part * 4;
            uint4* dst = (uint4*)(cframe + row * 260) + part * 4;
            uint4 s0 = src[0], s1 = src[1], s2 = src[2], s3 = src[3];
            dst[0] = s0; dst[1] = s1; dst[2] = s2; dst[3] = s3;
        }
        if (t < RPW)
            period_s[t] = (int)rintf(ld1f(f32, feats,
                (size_t)(b0 + t) * (NF * NFRAMES) + (NF - 1) * NFRAMES + f));
        __syncthreads();                                       // F2

        for (int kk = 0; kk < NSUB; ++kk) {
            // ================= BUILD (LDS-only) =================
            {
                int row = t >> 4, x16 = t & 15;
                unsigned int* cat32 = (unsigned int*)catb;
                int cb = row * 212;
                const unsigned int* cf = cframe + row * 260;
                int j4 = x16 * 4;
#pragma unroll
                for (int i = 0; i < 4; ++i) cat32[cb + j4 + i] = cf[kk * 64 + j4 + i];
                if (kk > 0) {
#pragma unroll
                    for (int i = 0; i < 4; ++i)
                        cat32[cb + 130 + j4 + i] = cf[(kk - 1) * 64 + j4 + i];
                }
                int per = period_s[row];
#pragma unroll
                for (int ii = 0; ii < 5; ++ii) {
                    int i = x16 * 5 + ii;
                    if (i < 68) {
                        int idx = LPREV - per + i - 2;
                        if (idx >= LPREV) idx -= per;
                        catb[row * 424 + 192 + i] = hist[row * 520 + ((base + idx) & 511)];
                    }
                }
            }
            __syncthreads();                                   // A

            // ================= FW (tanh), 2 chains =================
            {
                floatx4 C0 = z4, C1 = z4;
#pragma unroll
                for (int kb = 0; kb < 13; ++kb) {
                    short8 a = ldA(catb, 212, ln, kb, lq);
                    if (kb & 1) C1 = mf(a, Bfw[kb], C1);
                    else        C0 = mf(a, Bfw[kb], C0);
                }
#pragma unroll
                for (int r = 0; r < 4; ++r) {
                    int m = 4 * lq + r;
                    v64[m * 72 + nj] = f2bf(ftanh(C0[r] + C1[r]));
                }
            }
            __syncthreads();                                   // B

            // ================= FWG (glu); also stage sv[0] =================
            {
                floatx4 C = z4;
#pragma unroll
                for (int kb = 0; kb < 2; ++kb)
                    C = mf(ldA(v64, 36, ln, kb, lq), Bfwg[kb], C);
#pragma unroll
                for (int r = 0; r < 4; ++r) {
                    int m = 4 * lq + r;
                    float vp = bf2f(v64[m * 72 + nj]);
                    unsigned short ob = f2bf(vp * fsig(C[r]));
                    skx[m * 328 + 192 + nj] = ob;   // fw slot
                    xg [m * 200 + nj]       = ob;   // in0 for GRU1
                    xg [m * 200 + 128 + nj] = f2bf(svr[0][r]);   // s for GRU1
                }
            }
            __syncthreads();                                   // C

            // ================= GRU + GLU x3 =================
#pragma unroll
            for (int G = 0; G < 3; ++G) {
                {
                    floatx4 Cr = z4, Cz = z4, Ci = z4, Ch = z4;
#pragma unroll
                    for (int kb = 0; kb < 6; ++kb) {
                        short8 a = ldA(xg, 100, ln, kb, lq);
                        Cr = mf(a, Br[G][kb], Cr);
                        Cz = mf(a, Bz[G][kb], Cz);
                        if (kb < 4) Ci = mf(a, Bi[G][kb], Ci);
                        else        Ch = mf(a, Bh[G][kb - 4], Ch);
                    }
#pragma unroll
                    for (int r = 0; r < 4; ++r) {
                        int m = 4 * lq + r;
                        float rr = fsig(Cr[r]);
                        float zz = fsig(Cz[r]);
                        float nn = ftanh(Ci[r] + rr * Ch[r]);
                        float sn = fmaf(zz, svr[G][r] - nn, nn);
                        svr[G][r] = sn;
                        v64[m * 72 + nj] = f2bf(sn);
                    }
                }
                __syncthreads();                               // D/F/H
                {
                    floatx4 C = z4;
#pragma unroll
                    for (int kb = 0; kb < 2; ++kb)
                        C = mf(ldA(v64, 36, ln, kb, lq), Bg[G][kb], C);
#pragma unroll
                    for (int r = 0; r < 4; ++r) {
                        int m = 4 * lq + r;
                        unsigned short ob = f2bf(svr[G][r] * fsig(C[r]));
                        skx[m * 328 + G * 64 + nj] = ob;
                        if (G < 2) {
                            xg[m * 200 + nj]       = ob;                  // in0
                            xg[m * 200 + 128 + nj] = f2bf(svr[G + 1][r]); // s
                        }
                    }
                }
                __syncthreads();                               // E/G/I
            }

            // ================= SD (tanh), B from LDS, 4 chains =================
            {
                floatx4 C00 = z4, C01 = z4, C10 = z4, C11 = z4;
                int n0 = 32 * w + ln, n1 = n0 + 16;
#pragma unroll
                for (int kb = 0; kb < 10; ++kb) {
                    short8 a   = ldA(skx, 164, ln, kb, lq);
                    short8 b0f = ldA(wsd, 164, n0, kb, lq);
                    short8 b1f = ldA(wsd, 164, n1, kb, lq);
                    if (kb & 1) { C01 = mf(a, b0f, C01); C11 = mf(a, b1f, C11); }
                    else        { C00 = mf(a, b0f, C00); C10 = mf(a, b1f, C10); }
                }
#pragma unroll
                for (int r = 0; r < 4; ++r) {
                    int m = 4 * lq + r;
                    sdbb[m * 136 + n0] = f2bf(ftanh(C00[r] + C01[r]));
                    sdbb[m * 136 + n1] = f2bf(ftanh(C10[r] + C11[r]));
                }
            }
            __syncthreads();                                   // J

            // ================= SG (glu) =================
            {
                floatx4 C0 = z4, C1 = z4;
                int n0 = 32 * w + ln, n1 = n0 + 16;
#pragma unroll
                for (int kb = 0; kb < 4; ++kb) {
                    short8 a = ldA(sdbb, 68, ln, kb, lq);
                    C0 = mf(a, Bsg[0][kb], C0);
                    C1 = mf(a, Bsg[1][kb], C1);
                }
#pragma unroll
                for (int r = 0; r < 4; ++r) {
                    int m = 4 * lq + r;
                    float s0 = bf2f(sdbb[m * 136 + n0]);
                    float s1 = bf2f(sdbb[m * 136 + n1]);
                    sobb[m * 136 + n0] = f2bf(s0 * fsig(C0[r]));
                    sobb[m * 136 + n1] = f2bf(s1 * fsig(C1[r]));
                }
            }
            __syncthreads();                                   // K

            // ================= OUT (tanh) + prev_sub fusion =================
            {
                floatx4 C = z4;
#pragma unroll
                for (int kb = 0; kb < 4; ++kb)
                    C = mf(ldA(sobb, 68, ln, kb, lq), Bout[kb], C);
#pragma unroll
                for (int r = 0; r < 4; ++r) {
                    int m = 4 * lq + r;
                    float ov = ftanh(C[r]);
                    unsigned short ob = f2bf(ov);
                    hist[m * 520 + ((base + nj) & 511)] = ob;
                    catb[m * 424 + 128 + nj] = ob;
                    skx [m * 328 + 256 + nj] = ob;
                    xg  [m * 200 + 64  + nj] = ob;
                    if (f32) {
                        size_t oi = (size_t)(b0 + m) * (NFRAMES * NSUB * SS)
                                  + f * (NSUB * SS) + kk * SS + nj;
                        ((float*)outp)[oi] = ov;
                    }
                }
            }
            __syncthreads();                                   // L

            base += SS;
        }

        // ---- frame flush (bf16 mode): 256 samples/row from hist, no wrap ----
        if (!f32) {
            int row = t >> 4, x16 = t & 15;
            int fb2 = ((f & 1) ? 256 : 0) >> 1;    // frame base, u32 units (0 or 128)
            const unsigned int* hsrc = (const unsigned int*)hist + row * 260 + fb2 + x16 * 8;
            uint4 v0 = *(const uint4*)(hsrc);
            uint4 v1 = *(const uint4*)(hsrc + 4);
            unsigned short* op = (unsigned short*)outp
                + (size_t)(b0 + row) * (NFRAMES * 256) + f * 256 + x16 * 16;
            *(uint4*)(op)     = v0;
            *(uint4*)(op + 8) = v1;
        }
        // no barrier needed: next frame-top reads cframe/catb, disjoint from hist reads
    }
}

// ---------- launch ----------
extern "C" void kernel_launch(void* const* d_in, const int* in_sizes, int n_in,
                              void* d_out, int out_size, void* d_ws, size_t ws_size,
                              hipStream_t stream) {
    const void* feats = d_in[0];
    const void* gfeat = d_in[1];
    const void* prev  = d_in[2];
    const void* Wc1   = d_in[3];
    const void* Wc2   = d_in[4];
    const void* Wc3   = d_in[5];
    const void* Wfw   = d_in[6];
    const void* Wfwg  = d_in[7];
    const void* Wih1  = d_in[8];
    const void* Whh1  = d_in[9];
    const void* Wih2  = d_in[10];
    const void* Whh2  = d_in[11];
    const void* Wih3  = d_in[12];
    const void* Whh3  = d_in[13];
    const void* Wg1   = d_in[14];
    const void* Wg2   = d_in[15];
    const void* Wg3   = d_in[16];
    const void* Wsg   = d_in[17];
    const void* Wsd   = d_in[18];
    const void* Wout  = d_in[19];

    int*            flag = (int*)d_ws;                                   // @0
    unsigned short* cb16 = (unsigned short*)((char*)d_ws + 256);         // 6,553,600 B
    unsigned int*   wct  = (unsigned int*)((char*)d_ws + 256 + 6553600); // 524,288 B
    uint4*          wbuf = (uint4*)((char*)d_ws + 256 + 6553600 + 524288); // 438,272 B

    fargan_detect<<<1, 1, 0, stream>>>(feats, flag);
    fargan_prep<<<(NFRAG + 255) / 256, 256, 0, stream>>>(flag, Wfw, Wfwg,
        Wih1, Whh1, Wih2, Whh2, Wih3, Whh3, Wg1, Wg2, Wg3, Wsg, Wsd, Wout, wbuf);
    fargan_prep_conv<<<512, 256, 0, stream>>>(flag, Wc1, Wc2, Wc3, wct);
    fargan_conv<<<BATCH * NFRAMES, 256, 0, stream>>>(feats, gfeat, flag, wct, cb16);
    fargan_seq<<<BATCH / RPW, 256, 0, stream>>>(feats, prev, flag, cb16, wbuf, d_out);
}

// Round 11
// 2613.009 us; speedup vs baseline: 2.2386x; 1.0258x over previous
//
#include <hip/hip_runtime.h>
#include <hip/hip_bf16.h>

// FARGAN vocoder on MI355X. Sizes fixed by the reference:
#define SS      64
#define NSUB    4
#define LPREV   512
#define NF      193
#define NFRAMES 100
#define BATCH   64
#define RPW     16     // batch rows per workgroup (MFMA M)

typedef __attribute__((ext_vector_type(8))) short   short8;   // 8 bf16 (4 VGPRs)
typedef __attribute__((ext_vector_type(4))) float   floatx4;  // MFMA C/D

// ---------- scalar helpers ----------
__device__ __forceinline__ float bf2f(unsigned short u) {
    return __uint_as_float(((unsigned int)u) << 16);
}
__device__ __forceinline__ unsigned short f2bf(float x) {
    unsigned int u = __float_as_uint(x);
    return (unsigned short)((u + 0x7fffu + ((u >> 16) & 1u)) >> 16);
}
__device__ __forceinline__ unsigned int packbf(float a, float b) {
    return (unsigned int)f2bf(a) | ((unsigned int)f2bf(b) << 16);
}
__device__ __forceinline__ float fexp2(float x) {
#if __has_builtin(__builtin_amdgcn_exp2f)
    return __builtin_amdgcn_exp2f(x);
#else
    return exp2f(x);
#endif
}
__device__ __forceinline__ float frcp(float x) {
#if __has_builtin(__builtin_amdgcn_rcpf)
    return __builtin_amdgcn_rcpf(x);
#else
    return 1.0f / x;
#endif
}
__device__ __forceinline__ float fsig(float x) {
    return frcp(1.0f + fexp2(-1.442695041f * x));
}
__device__ __forceinline__ float ftanh(float x) {
    return fmaf(2.0f, frcp(1.0f + fexp2(-2.885390082f * x)), -1.0f);
}
__device__ __forceinline__ float ld1f(int f32, const void* p, size_t i) {
    if (f32) return ((const float*)p)[i];
    return bf2f(((const unsigned short*)p)[i]);
}
__device__ __forceinline__ float lo16(unsigned int u) { return __uint_as_float(u << 16); }
__device__ __forceinline__ float hi16(unsigned int u) { return __uint_as_float(u & 0xffff0000u); }

// MFMA wrapper
__device__ __forceinline__ floatx4 mf(short8 a, short8 b, floatx4 c) {
    return __builtin_amdgcn_mfma_f32_16x16x32_bf16(a, b, c, 0, 0, 0);
}

// A-fragment from packed-bf16 LDS buffer: row m, k-block kb, quad q.
__device__ __forceinline__ short8 ldA(const unsigned short* buf, int strideU,
                                      int m, int kb, int q) {
    const unsigned int* p = (const unsigned int*)buf + m * strideU + kb * 16 + q * 4;
    uint4 u = *(const uint4*)p;
    return __builtin_bit_cast(short8, u);
}
// B-fragment from prepacked weight buffer
__device__ __forceinline__ short8 ldB(const uint4* __restrict__ w, int idx) {
    return __builtin_bit_cast(short8, w[idx]);
}

// ---------- wbuf layout (units = 16B frags) ----------
#define OFF_FW   0        // 4t x 13kb
#define OFF_FWG  3328     // 4t x 2kb
#define OFF_GRU(G) (3840 + 4608*(G))   // r@+0(6kb) z@+1536(6kb) i@+3072(4kb) h@+4096(2kb)
#define OFF_WG(G)  (17664 + 512*(G))   // 4t x 2kb
#define OFF_SD   19200    // 8t x 10kb
#define OFF_SG   24320    // 8t x 4kb
#define OFF_OUT  26368    // 4t x 4kb
#define NFRAG    27392

// ---------- dtype detector ----------
__global__ void fargan_detect(const void* feats, int* flag) {
    const float* pf = (const float*)feats;
    int ok = 1;
    for (int f = 0; f < 50; ++f) {
        float v = pf[192 * NFRAMES + f];
        if (!(v >= 63.0f && v <= 301.0f)) { ok = 0; break; }
    }
    *flag = ok;
}

// ---------- weight prep: repack all seq weights into frag order ----------
__global__ __launch_bounds__(256) void fargan_prep(
    const int* __restrict__ flag,
    const void* Wfw, const void* Wfwg,
    const void* Wih1, const void* Whh1, const void* Wih2, const void* Whh2,
    const void* Wih3, const void* Whh3,
    const void* Wg1, const void* Wg2, const void* Wg3,
    const void* Wsg, const void* Wsd, const void* Wout,
    uint4* __restrict__ wbuf)
{
    int fi = blockIdx.x * 256 + threadIdx.x;
    if (fi >= NFRAG) return;
    int f32 = *flag;
    const void* mats[14] = {Wfw, Wfwg, Wih1, Whh1, Wih2, Whh2, Wih3, Whh3,
                            Wg1, Wg2, Wg3, Wsg, Wsd, Wout};
    const int NSEG = 20;
    const int sb[NSEG]  = {0,3328, 3840,5376,6912,7936, 8448,9984,11520,12544,
                           13056,14592,16128,17152, 17664,18176,18688, 19200,24320,26368};
    const int sa[NSEG]  = {0,1, 2,2,2,3, 4,4,4,5, 6,6,6,7, 8,9,10, 12,11,13};
    const int sbx[NSEG] = {-1,-1, 3,3,-1,-1, 5,5,-1,-1, 7,7,-1,-1, -1,-1,-1, -1,-1,-1};
    const int sro[NSEG] = {0,0, 0,64,128,128, 0,64,128,128, 0,64,128,128, 0,0,0, 0,0,0};
    const int skb[NSEG] = {13,2, 6,6,4,2, 6,6,4,2, 6,6,4,2, 2,2,2, 10,4,4};
    const int ska[NSEG] = {388,64, 128,128,128,64, 128,128,128,64, 128,128,128,64,
                           64,64,64, 320,128,128};
    const int skr[NSEG] = {388,64, 192,192,128,64, 192,192,128,64, 192,192,128,64,
                           64,64,64, 320,128,128};
    int s = 0;
    for (int i = 1; i < NSEG; ++i) if (fi >= sb[i]) s = i;
    int local = fi - sb[s];
    int ln = local & 15, lq = (local >> 4) & 3, tkb = local >> 6;
    int KB = skb[s];
    int kb = tkb % KB, tile = tkb / KB;
    int row = sro[s] + tile * 16 + ln;
    int Ka = ska[s], Kr = skr[s];
    union { unsigned short h[8]; uint4 v; } u;
#pragma unroll
    for (int j = 0; j < 8; ++j) {
        int k = kb * 32 + lq * 8 + j;
        unsigned short val = 0;
        if (k < Kr) {
            const void* m; size_t off;
            if (sbx[s] >= 0 && k >= Ka) { m = mats[sbx[s]]; off = (size_t)row * 64 + (k - Ka); }
            else                        { m = mats[sa[s]];  off = (size_t)row * Ka + k; }
            val = f32 ? f2bf(((const float*)m)[off]) : ((const unsigned short*)m)[off];
        }
        u.h[j] = val;
    }
    wbuf[fi] = u.v;
}

// ---------- prep: repack Wc1/2/3 transposed + bf16-pair packed ----------
__global__ __launch_bounds__(256) void fargan_prep_conv(
    const int* __restrict__ flag,
    const void* Wc1, const void* Wc2, const void* Wc3,
    unsigned int* __restrict__ wct)
{
    int idx = blockIdx.x * 256 + threadIdx.x;
    if (idx >= 131072) return;
    int f32 = *flag;
    const void* W; int n, k2;
    if (idx < 32768)      { W = Wc1; k2 = idx >> 8, n = idx & 255; }
    else if (idx < 65536) { W = Wc2; k2 = (idx - 32768) >> 8; n = idx & 255; }
    else                  { W = Wc3; k2 = (idx - 65536) >> 9; n = (idx - 65536) & 511; }
    size_t off = (size_t)n * 256 + 2 * k2;
    unsigned int v;
    if (f32) {
        const float* p = (const float*)W + off;
        v = packbf(p[0], p[1]);
    } else {
        v = *(const unsigned int*)((const unsigned short*)W + off);
    }
    wct[idx] = v;
}

// ---------- kernel 1: frame conv -> bf16 output cb16[b][f][k*128+j] ----------
template<bool F32>
__device__ __forceinline__ void conv_body(
    const void* __restrict__ feats, const void* __restrict__ gfeat,
    const unsigned int* __restrict__ wct, unsigned short* __restrict__ cb16)
{
    int blk = blockIdx.x;
    int b = blk / NFRAMES, f = blk - b * NFRAMES;
    int t = threadIdx.x;
    __shared__ float xa[256], xb[256];

    float v;
    if (t < 192) v = ld1f(F32 ? 1 : 0, feats, (size_t)b * (NF * NFRAMES) + t * NFRAMES + f);
    else         v = ld1f(F32 ? 1 : 0, gfeat, (size_t)b * 64 + (t - 192));
    xa[t] = v;
    __syncthreads();

    const unsigned int* w1 = wct;
    const unsigned int* w2 = wct + 32768;
    const unsigned int* w3 = wct + 65536;

    float a0 = 0.f, a1 = 0.f;
#pragma unroll 8
    for (int k2 = 0; k2 < 128; ++k2) {
        unsigned int u = w1[k2 * 256 + t];
        a0 = fmaf(lo16(u), xa[2 * k2], a0);
        a1 = fmaf(hi16(u), xa[2 * k2 + 1], a1);
    }
    xb[t] = ftanh(a0 + a1);
    __syncthreads();

    a0 = 0.f; a1 = 0.f;
#pragma unroll 8
    for (int k2 = 0; k2 < 128; ++k2) {
        unsigned int u = w2[k2 * 256 + t];
        a0 = fmaf(lo16(u), xb[2 * k2], a0);
        a1 = fmaf(hi16(u), xb[2 * k2 + 1], a1);
    }
    xa[t] = ftanh(a0 + a1);
    __syncthreads();

    a0 = 0.f; a1 = 0.f;
    float b0 = 0.f, b1 = 0.f;
#pragma unroll 8
    for (int k2 = 0; k2 < 128; ++k2) {
        unsigned int u = w3[k2 * 512 + t];
        unsigned int u2 = w3[k2 * 512 + t + 256];
        a0 = fmaf(lo16(u),  xa[2 * k2],     a0);
        a1 = fmaf(hi16(u),  xa[2 * k2 + 1], a1);
        b0 = fmaf(lo16(u2), xa[2 * k2],     b0);
        b1 = fmaf(hi16(u2), xa[2 * k2 + 1], b1);
    }
    unsigned short* co = cb16 + ((size_t)b * NFRAMES + f) * 512;
    // element e (= j*4+k) -> co[k*128 + j], bf16
    int e0 = t, e1 = t + 256;
    co[(e0 & 3) * 128 + (e0 >> 2)] = f2bf(ftanh(a0 + a1));
    co[(e1 & 3) * 128 + (e1 >> 2)] = f2bf(ftanh(b0 + b1));
}

__global__ __launch_bounds__(256) void fargan_conv(
    const void* feats, const void* gfeat,
    const int* flag, const unsigned int* wct, unsigned short* cb16)
{
    if (*flag) conv_body<true>(feats, gfeat, wct, cb16);
    else       conv_body<false>(feats, gfeat, wct, cb16);
}

// ---------- kernel 2: sequential recurrence (R7 structure + SD spreading) ----------
// 4 WGs x 16 rows, 4 waves n-split, resident weights, 1 wave/SIMD.
// SD's K-segments are accumulated incrementally in the GRU phases as their
// inputs become available (ps/fw in GRU1, o1 in GRU2, o2 in GRU3); the SD
// phase only adds o3 -> its serial MFMA chain shrinks from 20 to 4.

__global__ __launch_bounds__(256, 1) void fargan_seq(
    const void* __restrict__ feats, const void* __restrict__ prev_in,
    const int* __restrict__ flag, const unsigned short* __restrict__ cb16,
    const uint4* __restrict__ wbuf, void* __restrict__ outp)
{
    const int t = threadIdx.x;
    const int b0 = blockIdx.x * RPW;
    const int lane = t & 63, w = t >> 6;
    const int lq = lane >> 4, ln = lane & 15;
    const int nj = 16 * w + ln;            // n for 64-wide layers
    const int f32 = *flag;

    // ---- LDS (~142.6 KB) ----
    __shared__ __align__(16) unsigned short hist[RPW * 520];   // bf16 ring, mod-512
    __shared__ __align__(16) unsigned short catb[RPW * 424];   // [feat2s|ps|look|sfw|pad]
    __shared__ __align__(16) unsigned short xg  [RPW * 200];   // [in0|ps|s]
    __shared__ __align__(16) unsigned short skx [RPW * 328];   // [o1|o2|o3|fw|ps]
    __shared__ __align__(16) unsigned short sdbb[RPW * 136];
    __shared__ __align__(16) unsigned short sobb[RPW * 136];
    __shared__ __align__(16) unsigned short v64 [RPW * 72];    // vpre / svp (merged)
    __shared__ __align__(16) unsigned short wsd[128 * 328];    // Wsd, 164u stride
    __shared__ int period_s[RPW];

    // ---- resident B-fragments, coalesced preload from wbuf ----
    short8 Bfw[13], Bfwg[2], Bout[4];
    short8 Br[3][6], Bz[3][6], Bi[3][4], Bh[3][2], Bg[3][2];
    short8 Bsg[2][4];
#pragma unroll
    for (int kb = 0; kb < 13; ++kb) Bfw[kb] = ldB(wbuf, OFF_FW + (w * 13 + kb) * 64 + lane);
#pragma unroll
    for (int kb = 0; kb < 2; ++kb)  Bfwg[kb] = ldB(wbuf, OFF_FWG + (w * 2 + kb) * 64 + lane);
#pragma unroll
    for (int G = 0; G < 3; ++G) {
        const int OR = OFF_GRU(G), OZ = OR + 1536, OI = OR + 3072, OH = OR + 4096;
#pragma unroll
        for (int kb = 0; kb < 6; ++kb) {
            Br[G][kb] = ldB(wbuf, OR + (w * 6 + kb) * 64 + lane);
            Bz[G][kb] = ldB(wbuf, OZ + (w * 6 + kb) * 64 + lane);
        }
#pragma unroll
        for (int kb = 0; kb < 4; ++kb) Bi[G][kb] = ldB(wbuf, OI + (w * 4 + kb) * 64 + lane);
#pragma unroll
        for (int kb = 0; kb < 2; ++kb) {
            Bh[G][kb] = ldB(wbuf, OH + (w * 2 + kb) * 64 + lane);
            Bg[G][kb] = ldB(wbuf, OFF_WG(G) + (w * 2 + kb) * 64 + lane);
        }
    }
#pragma unroll
    for (int tile = 0; tile < 2; ++tile)
#pragma unroll
        for (int kb = 0; kb < 4; ++kb)
            Bsg[tile][kb] = ldB(wbuf, OFF_SG + ((2 * w + tile) * 4 + kb) * 64 + lane);
#pragma unroll
    for (int kb = 0; kb < 4; ++kb) Bout[kb] = ldB(wbuf, OFF_OUT + (w * 4 + kb) * 64 + lane);

    // ---- Wsd -> LDS from wbuf ----
    for (int fi = t; fi < 8 * 10 * 64; fi += 256) {
        int lane2 = fi & 63, tkb = fi >> 6;
        int kb = tkb % 10, tile = tkb / 10;
        int lq2 = lane2 >> 4, ln2 = lane2 & 15;
        int row = tile * 16 + ln2;
        uint4 v = wbuf[OFF_SD + fi];
        *(uint4*)((unsigned int*)wsd + row * 164 + kb * 16 + lq2 * 4) = v;
    }

    // ---- zero init LDS state + hist fill ----
    for (int i = t; i < RPW * 424; i += 256) catb[i] = 0;
    for (int i = t; i < RPW * 200; i += 256) xg[i] = 0;
    for (int i = t; i < RPW * 328; i += 256) skx[i] = 0;
    for (int i = t; i < RPW * 136; i += 256) { sdbb[i] = 0; sobb[i] = 0; }
    for (int i = t; i < RPW * 72;  i += 256) v64[i] = 0;
    for (int i = t; i < RPW * 512; i += 256) {
        int row = i >> 9, c = i & 511;
        hist[row * 520 + c] = f2bf(ld1f(f32, prev_in, (size_t)(b0 + row) * LPREV + c));
    }
    __syncthreads();
    // initial prev_sub slots (step 0): window[448..511] of prev_in
    for (int i = t; i < RPW * 64; i += 256) {
        int row = i >> 6, c = i & 63;
        unsigned short hh = hist[row * 520 + 448 + c];
        catb[row * 424 + 128 + c] = hh;
        skx [row * 328 + 256 + c] = hh;
        xg  [row * 200 + 64  + c] = hh;
    }

    // GRU states in C-layout registers: svr[G][r] = s[row 4lq+r][col nj]
    floatx4 svr[3];
#pragma unroll
    for (int G = 0; G < 3; ++G) svr[G] = (floatx4){0.f, 0.f, 0.f, 0.f};

    // ---- prefetch regs (16 threads/row, 8 bf16 each) ----
    const int prow = t >> 4, px16 = t & 15, pe8 = (t & 15) * 8;
    uint4 pfc;
    pfc = *(const uint4*)(cb16 + ((size_t)(b0 + prow) * NFRAMES + 0) * 512 + 0 * 128 + pe8);
    float pper = 0.f;
    if (t < RPW)
        pper = ld1f(f32, feats, (size_t)(b0 + t) * (NF * NFRAMES) + (NF - 1) * NFRAMES + 0);
    __syncthreads();

    const floatx4 z4 = {0.f, 0.f, 0.f, 0.f};
    int base = 0;
    for (int f = 0; f < NFRAMES; ++f) {
        if (t < RPW) period_s[t] = (int)rintf(pper);
        __syncthreads();
        if (t < RPW) {
            int fN = (f + 1 < NFRAMES) ? f + 1 : f;
            pper = ld1f(f32, feats, (size_t)(b0 + t) * (NF * NFRAMES) + (NF - 1) * NFRAMES + fN);
        }

        for (int kk = 0; kk < NSUB; ++kk) {
            // SD incremental C-fragments (chain by kb parity; tiles n0/n1)
            floatx4 SD00 = z4, SD01 = z4, SD10 = z4, SD11 = z4;
            const int n0 = 32 * w + ln, n1 = n0 + 16;

            // ================= BUILD (feat2s shuffle + lookback) =================
            {
                int row = prow;
                unsigned int* cat32 = (unsigned int*)catb;
                int cb = row * 212;
                int u0 = pe8 >> 1;
                // old feat2s -> sfw slot [260:388)
                unsigned int o0 = cat32[cb + u0 + 0];
                unsigned int o1 = cat32[cb + u0 + 1];
                unsigned int o2 = cat32[cb + u0 + 2];
                unsigned int o3 = cat32[cb + u0 + 3];
                cat32[cb + 130 + u0 + 0] = o0;
                cat32[cb + 130 + u0 + 1] = o1;
                cat32[cb + 130 + u0 + 2] = o2;
                cat32[cb + 130 + u0 + 3] = o3;
                *(uint4*)(cat32 + cb + u0) = pfc;   // new feat2s (bf16 pairs)
                // prefetch next step's crow
                {
                    int sN = f * 4 + kk + 1;
                    if (sN > NFRAMES * 4 - 1) sN = NFRAMES * 4 - 1;
                    int fN = sN >> 2, kN = sN & 3;
                    pfc = *(const uint4*)(cb16
                        + ((size_t)(b0 + row) * NFRAMES + fN) * 512 + kN * 128 + pe8);
                }
                // lookback -> cat[192:260)
                int per = period_s[row];
#pragma unroll
                for (int ii = 0; ii < 5; ++ii) {
                    int i = px16 * 5 + ii;
                    if (i < 68) {
                        int idx = LPREV - per + i - 2;
                        if (idx >= LPREV) idx -= per;
                        catb[row * 424 + 192 + i] = hist[row * 520 + ((base + idx) & 511)];
                    }
                }
            }
            __syncthreads();                                   // A

            // ================= FW (tanh), 4 chains =================
            {
                floatx4 C0 = z4, C1 = z4, C2 = z4, C3 = z4;
#pragma unroll
                for (int kb = 0; kb < 13; ++kb) {
                    short8 a = ldA(catb, 212, ln, kb, lq);
                    switch (kb & 3) {
                        case 0: C0 = mf(a, Bfw[kb], C0); break;
                        case 1: C1 = mf(a, Bfw[kb], C1); break;
                        case 2: C2 = mf(a, Bfw[kb], C2); break;
                        default: C3 = mf(a, Bfw[kb], C3); break;
                    }
                }
#pragma unroll
                for (int r = 0; r < 4; ++r) {
                    int m = 4 * lq + r;
                    v64[m * 72 + nj] = f2bf(ftanh((C0[r] + C1[r]) + (C2[r] + C3[r])));
                }
            }
            __syncthreads();                                   // B

            // ================= FWG (glu); also stage sv[0] =================
            {
                floatx4 C = z4;
#pragma unroll
                for (int kb = 0; kb < 2; ++kb)
                    C = mf(ldA(v64, 36, ln, kb, lq), Bfwg[kb], C);
#pragma unroll
                for (int r = 0; r < 4; ++r) {
                    int m = 4 * lq + r;
                    float vp = bf2f(v64[m * 72 + nj]);
                    unsigned short ob = f2bf(vp * fsig(C[r]));
                    skx[m * 328 + 192 + nj] = ob;   // fw slot
                    xg [m * 200 + nj]       = ob;   // in0 for GRU1
                    xg [m * 200 + 128 + nj] = f2bf(svr[0][r]);   // s for GRU1
                }
            }
            __syncthreads();                                   // C

            // ================= GRU + GLU x3 (+ SD segment accumulation) ======
#pragma unroll
            for (int G = 0; G < 3; ++G) {
                {
                    floatx4 Cr = z4, Cz = z4, Ci = z4, Ch = z4;
#pragma unroll
                    for (int kb = 0; kb < 6; ++kb) {
                        short8 a = ldA(xg, 100, ln, kb, lq);
                        Cr = mf(a, Br[G][kb], Cr);
                        Cz = mf(a, Bz[G][kb], Cz);
                        if (kb < 4) Ci = mf(a, Bi[G][kb], Ci);
                        else        Ch = mf(a, Bh[G][kb - 4], Ch);
                    }
                    // SD segments whose inputs are ready:
                    //   G==0: fw(kb6,7) + ps(kb8,9);  G==1: o1(kb0,1);  G==2: o2(kb2,3)
                    {
                        int kbs = (G == 0) ? 6 : (G == 1) ? 0 : 2;
                        int nkb = (G == 0) ? 4 : 2;
#pragma unroll
                        for (int j = 0; j < 4; ++j) {
                            if (j < nkb) {
                                int kb = kbs + j;
                                short8 a   = ldA(skx, 164, ln, kb, lq);
                                short8 b0f = ldA(wsd, 164, n0, kb, lq);
                                short8 b1f = ldA(wsd, 164, n1, kb, lq);
                                if (kb & 1) { SD01 = mf(a, b0f, SD01); SD11 = mf(a, b1f, SD11); }
                                else        { SD00 = mf(a, b0f, SD00); SD10 = mf(a, b1f, SD10); }
                            }
                        }
                    }
#pragma unroll
                    for (int r = 0; r < 4; ++r) {
                        int m = 4 * lq + r;
                        float rr = fsig(Cr[r]);
                        float zz = fsig(Cz[r]);
                        float nn = ftanh(Ci[r] + rr * Ch[r]);
                        float sn = fmaf(zz, svr[G][r] - nn, nn);
                        svr[G][r] = sn;
                        v64[m * 72 + nj] = f2bf(sn);
                    }
                }
                __syncthreads();                               // D/F/H
                {
                    floatx4 C = z4;
#pragma unroll
                    for (int kb = 0; kb < 2; ++kb)
                        C = mf(ldA(v64, 36, ln, kb, lq), Bg[G][kb], C);
#pragma unroll
                    for (int r = 0; r < 4; ++r) {
                        int m = 4 * lq + r;
                        unsigned short ob = f2bf(svr[G][r] * fsig(C[r]));
                        skx[m * 328 + G * 64 + nj] = ob;
                        if (G < 2) {
                            xg[m * 200 + nj]       = ob;                  // in0
                            xg[m * 200 + 128 + nj] = f2bf(svr[G + 1][r]); // s
                        }
                    }
                }
                __syncthreads();                               // E/G/I
            }

            // ================= SD (tanh): only o3 (kb4,5) remains ============
            {
#pragma unroll
                for (int j = 0; j < 2; ++j) {
                    int kb = 4 + j;
                    short8 a   = ldA(skx, 164, ln, kb, lq);
                    short8 b0f = ldA(wsd, 164, n0, kb, lq);
                    short8 b1f = ldA(wsd, 164, n1, kb, lq);
                    if (kb & 1) { SD01 = mf(a, b0f, SD01); SD11 = mf(a, b1f, SD11); }
                    else        { SD00 = mf(a, b0f, SD00); SD10 = mf(a, b1f, SD10); }
                }
#pragma unroll
                for (int r = 0; r < 4; ++r) {
                    int m = 4 * lq + r;
                    sdbb[m * 136 + n0] = f2bf(ftanh(SD00[r] + SD01[r]));
                    sdbb[m * 136 + n1] = f2bf(ftanh(SD10[r] + SD11[r]));
                }
            }
            __syncthreads();                                   // J

            // ================= SG (glu) =================
            {
                floatx4 C0 = z4, C1 = z4;
#pragma unroll
                for (int kb = 0; kb < 4; ++kb) {
                    short8 a = ldA(sdbb, 68, ln, kb, lq);
                    C0 = mf(a, Bsg[0][kb], C0);
                    C1 = mf(a, Bsg[1][kb], C1);
                }
#pragma unroll
                for (int r = 0; r < 4; ++r) {
                    int m = 4 * lq + r;
                    float s0 = bf2f(sdbb[m * 136 + n0]);
                    float s1 = bf2f(sdbb[m * 136 + n1]);
                    sobb[m * 136 + n0] = f2bf(s0 * fsig(C0[r]));
                    sobb[m * 136 + n1] = f2bf(s1 * fsig(C1[r]));
                }
            }
            __syncthreads();                                   // K

            // ================= OUT (tanh) + prev_sub fusion =================
            {
                floatx4 C = z4;
#pragma unroll
                for (int kb = 0; kb < 4; ++kb)
                    C = mf(ldA(sobb, 68, ln, kb, lq), Bout[kb], C);
#pragma unroll
                for (int r = 0; r < 4; ++r) {
                    int m = 4 * lq + r;
                    float ov = ftanh(C[r]);
                    unsigned short ob = f2bf(ov);
                    hist[m * 520 + ((base + nj) & 511)] = ob;
                    catb[m * 424 + 128 + nj] = ob;
                    skx [m * 328 + 256 + nj] = ob;
                    xg  [m * 200 + 64  + nj] = ob;
                    size_t oi = (size_t)(b0 + m) * (NFRAMES * NSUB * SS)
                              + f * (NSUB * SS) + kk * SS + nj;
                    if (f32) ((float*)outp)[oi] = ov;
                    else     ((unsigned short*)outp)[oi] = ob;
                }
            }
            __syncthreads();                                   // L

            base += SS;
        }
    }
}

// ---------- launch ----------
extern "C" void kernel_launch(void* const* d_in, const int* in_sizes, int n_in,
                              void* d_out, int out_size, void* d_ws, size_t ws_size,
                              hipStream_t stream) {
    const void* feats = d_in[0];
    const void* gfeat = d_in[1];
    const void* prev  = d_in[2];
    const void* Wc1   = d_in[3];
    const void* Wc2   = d_in[4];
    const void* Wc3   = d_in[5];
    const void* Wfw   = d_in[6];
    const void* Wfwg  = d_in[7];
    const void* Wih1  = d_in[8];
    const void* Whh1  = d_in[9];
    const void* Wih2  = d_in[10];
    const void* Whh2  = d_in[11];
    const void* Wih3  = d_in[12];
    const void* Whh3  = d_in[13];
    const void* Wg1   = d_in[14];
    const void* Wg2   = d_in[15];
    const void* Wg3   = d_in[16];
    const void* Wsg   = d_in[17];
    const void* Wsd   = d_in[18];
    const void* Wout  = d_in[19];

    int*            flag = (int*)d_ws;                                      // @0
    unsigned short* cb16 = (unsigned short*)((char*)d_ws + 256);            // 6,553,600 B
    unsigned int*   wct  = (unsigned int*)((char*)d_ws + 256 + 6553600);    // 524,288 B
    uint4*          wbuf = (uint4*)((char*)d_ws + 256 + 6553600 + 524288);  // 438,272 B

    fargan_detect<<<1, 1, 0, stream>>>(feats, flag);
    fargan_prep<<<(NFRAG + 255) / 256, 256, 0, stream>>>(flag, Wfw, Wfwg,
        Wih1, Whh1, Wih2, Whh2, Wih3, Whh3, Wg1, Wg2, Wg3, Wsg, Wsd, Wout, wbuf);
    fargan_prep_conv<<<512, 256, 0, stream>>>(flag, Wc1, Wc2, Wc3, wct);
    fargan_conv<<<BATCH * NFRAMES, 256, 0, stream>>>(feats, gfeat, flag, wct, cb16);
    fargan_seq<<<BATCH / RPW, 256, 0, stream>>>(feats, prev, flag, cb16, wbuf, d_out);
}